// Round 2
// baseline (1671.757 us; speedup 1.0000x reference)
//
#include <hip/hip_runtime.h>
#include <cstdint>
#include <math.h>

#define BLK 256

// ---------------- degree / dinv ----------------

__global__ void k_init_deg(float* __restrict__ deg, int n) {
  int i = blockIdx.x * blockDim.x + threadIdx.x;
  if (i < n) deg[i] = 1.0f;  // self-loop counts once
}

__global__ void k_deg_scatter(const int* __restrict__ edges, long long E,
                              float* __restrict__ deg) {
  long long t = (long long)blockIdx.x * blockDim.x + threadIdx.x;
  long long stride = (long long)gridDim.x * blockDim.x;
  for (; t < E; t += stride) {
    int d = edges[E + t];  // dst row
    atomicAdd(&deg[d], 1.0f);
  }
}

__global__ void k_dinv(float* __restrict__ deg, int n) {
  int i = blockIdx.x * blockDim.x + threadIdx.x;
  if (i < n) deg[i] = rsqrtf(deg[i]);  // deg >= 1 always (self-loop)
}

// ---------------- dense node-wise GEMM: out[v] = (relu?)in[v] @ W ----------------
// W (K x OUT) staged in LDS; thread-per-node; acc[OUT] in VGPRs.
// LDS reads are same-address across the wave -> broadcast.

template<int K, int OUT, bool RELU_IN>
__global__ __launch_bounds__(BLK)
void k_gemm(const float* __restrict__ in, const float* __restrict__ W,
            float* __restrict__ out, int n) {
  __shared__ float Wl[K * OUT];
  for (int i = threadIdx.x; i < K * OUT; i += BLK) Wl[i] = W[i];
  __syncthreads();

  int v = blockIdx.x * BLK + threadIdx.x;
  if (v >= n) return;

  float acc[OUT];
#pragma unroll
  for (int o = 0; o < OUT; ++o) acc[o] = 0.f;

  const float* __restrict__ row = in + (size_t)v * K;
  for (int k = 0; k < K; ++k) {
    float xv = row[k];
    if (RELU_IN) xv = fmaxf(xv, 0.f);
    const float* wr = &Wl[k * OUT];
#pragma unroll
    for (int o = 0; o < OUT; ++o) acc[o] += xv * wr[o];
  }

  float* orow = out + (size_t)v * OUT;
#pragma unroll
  for (int o = 0; o < OUT; ++o) orow[o] = acc[o];
}

// ---------------- aggregation ----------------
// agg[v][c] = h[v][c]*dinv[v]^2 + b[c]   (self-loop + bias; full overwrite, no memset needed)

template<int C>
__global__ void k_selfloop_bias(const float* __restrict__ h, const float* __restrict__ dinv,
                                const float* __restrict__ b, float* __restrict__ agg,
                                unsigned long long total) {
  unsigned long long t = (unsigned long long)blockIdx.x * blockDim.x + threadIdx.x;
  unsigned long long stride = (unsigned long long)gridDim.x * blockDim.x;
  for (; t < total; t += stride) {
    unsigned int v = (unsigned int)(t / C);
    unsigned int c = (unsigned int)(t % C);
    float d = dinv[v];
    agg[t] = fmaf(h[t], d * d, b[c]);
  }
}

// agg[dst][c] += h[src][c] * dinv[src]*dinv[dst]  for each edge
// t consecutive -> c fastest: for C>=wavefront chunks, gather and atomic are coalesced.

template<int C>
__global__ void k_edge_scatter(const float* __restrict__ h, const float* __restrict__ dinv,
                               const int* __restrict__ edges, long long E,
                               float* __restrict__ agg) {
  unsigned long long total = (unsigned long long)E * C;
  unsigned long long t = (unsigned long long)blockIdx.x * blockDim.x + threadIdx.x;
  unsigned long long stride = (unsigned long long)gridDim.x * blockDim.x;
  for (; t < total; t += stride) {
    unsigned long long e = t / C;
    unsigned int c = (unsigned int)(t % C);
    int s = edges[e];
    int d = edges[E + e];
    float nrm = dinv[s] * dinv[d];
    atomicAdd(&agg[(size_t)d * C + c], h[(size_t)s * C + c] * nrm);
  }
}

// ---------------- final 2-class log-softmax ----------------

__global__ void k_logsoftmax2(const float* __restrict__ agg, float* __restrict__ out, int n) {
  int v = blockIdx.x * blockDim.x + threadIdx.x;
  if (v < n) {
    float a = agg[2 * v];
    float b = agg[2 * v + 1];
    float m = fmaxf(a, b);
    float l = m + logf(expf(a - m) + expf(b - m));
    out[2 * v] = a - l;
    out[2 * v + 1] = b - l;
  }
}

// ---------------- launch ----------------

static inline int nb(long long total, int cap = 16384) {
  long long b = (total + BLK - 1) / BLK;
  if (b > cap) b = cap;
  if (b < 1) b = 1;
  return (int)b;
}

extern "C" void kernel_launch(void* const* d_in, const int* in_sizes, int n_in,
                              void* d_out, int out_size, void* d_ws, size_t ws_size,
                              hipStream_t stream) {
  const float* x = (const float*)d_in[0];
  const int* edges = (const int*)d_in[1];   // int32! harness delivers integer inputs as int32
  const float* W1 = (const float*)d_in[2];
  const float* b1 = (const float*)d_in[3];
  const float* W2 = (const float*)d_in[4];
  const float* b2 = (const float*)d_in[5];
  const float* W3 = (const float*)d_in[6];
  const float* b3 = (const float*)d_in[7];
  float* out = (float*)d_out;

  const int N = in_sizes[0] / 165;
  const long long E = in_sizes[1] / 2;

  float* ws = (float*)d_ws;
  float* dinv = ws;                         // N floats (deg then dinv, in place)
  float* bufA = ws + N;                     // N*64 floats (h1 / h2 / h3)
  float* bufB = bufA + (size_t)N * 64;      // N*64 floats (agg1 / agg2 / agg3)

  const int gN = (N + BLK - 1) / BLK;

  // degree + dinv
  k_init_deg<<<gN, BLK, 0, stream>>>(dinv, N);
  k_deg_scatter<<<nb(E), BLK, 0, stream>>>(edges, E, dinv);
  k_dinv<<<gN, BLK, 0, stream>>>(dinv, N);

  // ---- layer 1: 165 -> 64 ----
  k_gemm<165, 64, false><<<gN, BLK, 0, stream>>>(x, W1, bufA, N);
  k_selfloop_bias<64><<<nb((long long)N * 64), BLK, 0, stream>>>(
      bufA, dinv, b1, bufB, (unsigned long long)N * 64);
  k_edge_scatter<64><<<nb(E * 64), BLK, 0, stream>>>(bufA, dinv, edges, E, bufB);

  // ---- layer 2: 64 -> 16 (relu on load of agg1) ----
  k_gemm<64, 16, true><<<gN, BLK, 0, stream>>>(bufB, W2, bufA, N);
  k_selfloop_bias<16><<<nb((long long)N * 16), BLK, 0, stream>>>(
      bufA, dinv, b2, bufB, (unsigned long long)N * 16);
  k_edge_scatter<16><<<nb(E * 16), BLK, 0, stream>>>(bufA, dinv, edges, E, bufB);

  // ---- layer 3: 16 -> 2 (relu on load of agg2) ----
  k_gemm<16, 2, true><<<gN, BLK, 0, stream>>>(bufB, W3, bufA, N);
  k_selfloop_bias<2><<<nb((long long)N * 2), BLK, 0, stream>>>(
      bufA, dinv, b3, bufB, (unsigned long long)N * 2);
  k_edge_scatter<2><<<nb(E * 2), BLK, 0, stream>>>(bufA, dinv, edges, E, bufB);

  // ---- log-softmax ----
  k_logsoftmax2<<<gN, BLK, 0, stream>>>(bufB, out, N);
}

// Round 3
// 1203.657 us; speedup vs baseline: 1.3889x; 1.3889x over previous
//
#include <hip/hip_runtime.h>
#include <cstdint>
#include <math.h>

#define BLK 256

// ================= CSR build =================

__global__ void k_zero(int* __restrict__ p, int n) {
  int i = blockIdx.x * blockDim.x + threadIdx.x;
  if (i < n) p[i] = 0;
}

__global__ void k_hist(const int* __restrict__ edges, long long E, int* __restrict__ counts) {
  long long t = (long long)blockIdx.x * blockDim.x + threadIdx.x;
  long long stride = (long long)gridDim.x * blockDim.x;
  for (; t < E; t += stride) atomicAdd(&counts[edges[E + t]], 1);
}

// per-block inclusive scan -> exclusive row_start (block-local), block totals out
__global__ __launch_bounds__(BLK)
void k_scan_block(const int* __restrict__ counts, int n,
                  int* __restrict__ row_start, int* __restrict__ blockSums) {
  __shared__ int tmp[BLK];
  int i = blockIdx.x * BLK + threadIdx.x;
  int v = (i < n) ? counts[i] : 0;
  tmp[threadIdx.x] = v;
  __syncthreads();
  for (int off = 1; off < BLK; off <<= 1) {
    int t = (threadIdx.x >= (unsigned)off) ? tmp[threadIdx.x - off] : 0;
    __syncthreads();
    tmp[threadIdx.x] += t;
    __syncthreads();
  }
  if (i < n) row_start[i] = tmp[threadIdx.x] - v;  // exclusive
  if (threadIdx.x == BLK - 1) blockSums[blockIdx.x] = tmp[BLK - 1];
}

// single-block exclusive scan of block sums (nb <= 1024)
__global__ __launch_bounds__(1024)
void k_scan_sums(int* __restrict__ blockSums, int nb) {
  __shared__ int tmp[1024];
  int i = threadIdx.x;
  int v = (i < nb) ? blockSums[i] : 0;
  tmp[i] = v;
  __syncthreads();
  for (int off = 1; off < 1024; off <<= 1) {
    int t = (i >= off) ? tmp[i - off] : 0;
    __syncthreads();
    tmp[i] += t;
    __syncthreads();
  }
  if (i < nb) blockSums[i] = tmp[i] - v;  // exclusive
}

// add block offsets; init cursor; also compute dinv = rsqrt(count+1)
__global__ void k_scan_add(int* __restrict__ row_start, const int* __restrict__ blockSums,
                           int* __restrict__ cursor, const int* __restrict__ counts,
                           float* __restrict__ dinv, int n) {
  int i = blockIdx.x * BLK + threadIdx.x;
  if (i < n) {
    int rs = row_start[i] + blockSums[blockIdx.x];
    row_start[i] = rs;
    cursor[i] = rs;
    dinv[i] = rsqrtf((float)counts[i] + 1.0f);  // +1 self-loop
  }
}

__global__ void k_fill(const int* __restrict__ edges, long long E,
                       int* __restrict__ cursor, int* __restrict__ col) {
  long long t = (long long)blockIdx.x * blockDim.x + threadIdx.x;
  long long stride = (long long)gridDim.x * blockDim.x;
  for (; t < E; t += stride) {
    int s = edges[t];
    int d = edges[E + t];
    int pos = atomicAdd(&cursor[d], 1);
    col[pos] = s;
  }
}

// ================= dense node-wise GEMM: hs[v] = ((relu?)in[v] @ W) * dinv[v] =================

template<int K, int OUT, bool RELU_IN>
__global__ __launch_bounds__(BLK)
void k_gemm(const float* __restrict__ in, const float* __restrict__ W,
            const float* __restrict__ dinv, float* __restrict__ out, int n) {
  __shared__ float Wl[K * OUT];
  for (int i = threadIdx.x; i < K * OUT; i += BLK) Wl[i] = W[i];
  __syncthreads();

  int v = blockIdx.x * BLK + threadIdx.x;
  if (v >= n) return;

  float acc[OUT];
#pragma unroll
  for (int o = 0; o < OUT; ++o) acc[o] = 0.f;

  const float* __restrict__ row = in + (size_t)v * K;
  for (int k = 0; k < K; ++k) {
    float xv = row[k];
    if (RELU_IN) xv = fmaxf(xv, 0.f);
    const float* wr = &Wl[k * OUT];
#pragma unroll
    for (int o = 0; o < OUT; ++o) acc[o] += xv * wr[o];
  }

  float dv = dinv[v];
  float* orow = out + (size_t)v * OUT;
#pragma unroll
  for (int o = 0; o < OUT; ++o) orow[o] = acc[o] * dv;
}

// ================= CSR gather aggregation =================
// out[v][c] = dinv[v] * ( sum_{s in N(v)} hs[s][c] + hs[v][c] ) + b[c]
// (hs already scaled by dinv[src]; self-loop term = dinv[v]^2*h[v][c])

// C=64: one wave per node, lane = channel
__global__ __launch_bounds__(BLK)
void k_gather64(const float* __restrict__ hs, const int* __restrict__ row_start,
                const int* __restrict__ counts, const int* __restrict__ col,
                const float* __restrict__ dinv, const float* __restrict__ b,
                float* __restrict__ out, int n) {
  int wave = threadIdx.x >> 6, lane = threadIdx.x & 63;
  int v = blockIdx.x * 4 + wave;
  if (v >= n) return;
  int beg = row_start[v], cnt = counts[v];
  float acc = hs[(size_t)v * 64 + lane];  // self-loop
  int e = 0;
  for (; e + 1 < cnt; e += 2) {
    int s0 = col[beg + e];
    int s1 = col[beg + e + 1];
    acc += hs[(size_t)s0 * 64 + lane];
    acc += hs[(size_t)s1 * 64 + lane];
  }
  if (e < cnt) acc += hs[(size_t)col[beg + e] * 64 + lane];
  out[(size_t)v * 64 + lane] = fmaf(acc, dinv[v], b[lane]);
}

// C=16: one wave per node; lane = (edge-slot j=lane>>4, channel c=lane&15)
__global__ __launch_bounds__(BLK)
void k_gather16(const float* __restrict__ hs, const int* __restrict__ row_start,
                const int* __restrict__ counts, const int* __restrict__ col,
                const float* __restrict__ dinv, const float* __restrict__ b,
                float* __restrict__ out, int n) {
  int wave = threadIdx.x >> 6, lane = threadIdx.x & 63;
  int v = blockIdx.x * 4 + wave;
  if (v >= n) return;
  int c = lane & 15, j = lane >> 4;
  int beg = row_start[v], cnt = counts[v];
  float acc = 0.f;
  for (int e = j; e < cnt; e += 4) acc += hs[(size_t)col[beg + e] * 16 + c];
  acc += __shfl_xor(acc, 16);
  acc += __shfl_xor(acc, 32);
  if (j == 0)
    out[(size_t)v * 16 + c] = fmaf(acc + hs[(size_t)v * 16 + c], dinv[v], b[c]);
}

// C=2 gather + bias + log-softmax fused: one thread per node
__global__ void k_gather2_lsm(const float* __restrict__ hs, const int* __restrict__ row_start,
                              const int* __restrict__ counts, const int* __restrict__ col,
                              const float* __restrict__ dinv, const float* __restrict__ b,
                              float* __restrict__ out, int n) {
  int v = blockIdx.x * blockDim.x + threadIdx.x;
  if (v >= n) return;
  const float2* hs2 = (const float2*)hs;
  int beg = row_start[v], cnt = counts[v];
  float2 self = hs2[v];
  float a0 = self.x, a1 = self.y;
  for (int e = 0; e < cnt; ++e) {
    float2 m = hs2[col[beg + e]];
    a0 += m.x;
    a1 += m.y;
  }
  float dv = dinv[v];
  a0 = fmaf(a0, dv, b[0]);
  a1 = fmaf(a1, dv, b[1]);
  float m = fmaxf(a0, a1);
  float l = m + logf(expf(a0 - m) + expf(a1 - m));
  out[2 * v] = a0 - l;
  out[2 * v + 1] = a1 - l;
}

// ================= launch =================

static inline int nb(long long total, int cap = 65535) {
  long long b = (total + BLK - 1) / BLK;
  if (b > cap) b = cap;
  if (b < 1) b = 1;
  return (int)b;
}

extern "C" void kernel_launch(void* const* d_in, const int* in_sizes, int n_in,
                              void* d_out, int out_size, void* d_ws, size_t ws_size,
                              hipStream_t stream) {
  const float* x = (const float*)d_in[0];
  const int* edges = (const int*)d_in[1];   // int32
  const float* W1 = (const float*)d_in[2];
  const float* b1 = (const float*)d_in[3];
  const float* W2 = (const float*)d_in[4];
  const float* b2 = (const float*)d_in[5];
  const float* W3 = (const float*)d_in[6];
  const float* b3 = (const float*)d_in[7];
  float* out = (float*)d_out;

  const int N = in_sizes[0] / 165;
  const long long E = in_sizes[1] / 2;

  // workspace layout
  char* w = (char*)d_ws;
  int* counts    = (int*)w;               w += (size_t)N * 4;
  int* row_start = (int*)w;               w += (size_t)N * 4;
  int* cursor    = (int*)w;               w += (size_t)N * 4;
  int* blockSums = (int*)w;               w += 1024 * 4;
  int* col       = (int*)w;               w += (size_t)E * 4;
  float* dinv    = (float*)w;             w += (size_t)N * 4;
  float* bufA    = (float*)w;             w += (size_t)N * 64 * 4;
  float* bufB    = (float*)w;             // N*64*4

  const int gN = (N + BLK - 1) / BLK;       // 782 blocks (<=1024 for scan)
  const int gW = (N + 3) / 4;               // wave-per-node grids

  // ---- CSR build + dinv ----
  k_zero<<<gN, BLK, 0, stream>>>(counts, N);
  k_hist<<<nb(E), BLK, 0, stream>>>(edges, E, counts);
  k_scan_block<<<gN, BLK, 0, stream>>>(counts, N, row_start, blockSums);
  k_scan_sums<<<1, 1024, 0, stream>>>(blockSums, gN);
  k_scan_add<<<gN, BLK, 0, stream>>>(row_start, blockSums, cursor, counts, dinv, N);
  k_fill<<<nb(E), BLK, 0, stream>>>(edges, E, cursor, col);

  // ---- layer 1: 165 -> 64 ----
  k_gemm<165, 64, false><<<gN, BLK, 0, stream>>>(x, W1, dinv, bufA, N);
  k_gather64<<<gW, BLK, 0, stream>>>(bufA, row_start, counts, col, dinv, b1, bufB, N);

  // ---- layer 2: 64 -> 16 (relu folded into gemm load) ----
  k_gemm<64, 16, true><<<gN, BLK, 0, stream>>>(bufB, W2, dinv, bufA, N);
  k_gather16<<<gW, BLK, 0, stream>>>(bufA, row_start, counts, col, dinv, b2, bufB, N);

  // ---- layer 3: 16 -> 2 + log-softmax fused into gather ----
  k_gemm<16, 2, true><<<gN, BLK, 0, stream>>>(bufB, W3, dinv, bufA, N);
  k_gather2_lsm<<<gN, BLK, 0, stream>>>(bufA, row_start, counts, col, dinv, b3, out, N);
}

// Round 4
// 1186.431 us; speedup vs baseline: 1.4091x; 1.0145x over previous
//
#include <hip/hip_runtime.h>
#include <cstdint>
#include <math.h>

#define BLK 256

// ================= CSR build =================

__global__ void k_zero(int* __restrict__ p, int n) {
  int i = blockIdx.x * blockDim.x + threadIdx.x;
  if (i < n) p[i] = 0;
}

__global__ void k_hist(const int* __restrict__ edges, long long E, int* __restrict__ counts) {
  long long t = (long long)blockIdx.x * blockDim.x + threadIdx.x;
  long long stride = (long long)gridDim.x * blockDim.x;
  for (; t < E; t += stride) atomicAdd(&counts[edges[E + t]], 1);
}

__global__ __launch_bounds__(BLK)
void k_scan_block(const int* __restrict__ counts, int n,
                  int* __restrict__ row_start, int* __restrict__ blockSums) {
  __shared__ int tmp[BLK];
  int i = blockIdx.x * BLK + threadIdx.x;
  int v = (i < n) ? counts[i] : 0;
  tmp[threadIdx.x] = v;
  __syncthreads();
  for (int off = 1; off < BLK; off <<= 1) {
    int t = (threadIdx.x >= (unsigned)off) ? tmp[threadIdx.x - off] : 0;
    __syncthreads();
    tmp[threadIdx.x] += t;
    __syncthreads();
  }
  if (i < n) row_start[i] = tmp[threadIdx.x] - v;  // exclusive
  if (threadIdx.x == BLK - 1) blockSums[blockIdx.x] = tmp[BLK - 1];
}

__global__ __launch_bounds__(1024)
void k_scan_sums(int* __restrict__ blockSums, int nb) {
  __shared__ int tmp[1024];
  int i = threadIdx.x;
  int v = (i < nb) ? blockSums[i] : 0;
  tmp[i] = v;
  __syncthreads();
  for (int off = 1; off < 1024; off <<= 1) {
    int t = (i >= off) ? tmp[i - off] : 0;
    __syncthreads();
    tmp[i] += t;
    __syncthreads();
  }
  if (i < nb) blockSums[i] = tmp[i] - v;  // exclusive
}

__global__ void k_scan_add(int* __restrict__ row_start, const int* __restrict__ blockSums,
                           int* __restrict__ cursor, const int* __restrict__ counts,
                           float* __restrict__ dinv, int n) {
  int i = blockIdx.x * BLK + threadIdx.x;
  if (i < n) {
    int rs = row_start[i] + blockSums[blockIdx.x];
    row_start[i] = rs;
    cursor[i] = rs;
    dinv[i] = rsqrtf((float)counts[i] + 1.0f);  // +1 self-loop
  }
}

__global__ void k_fill(const int* __restrict__ edges, long long E,
                       int* __restrict__ cursor, int* __restrict__ col) {
  long long t = (long long)blockIdx.x * blockDim.x + threadIdx.x;
  long long stride = (long long)gridDim.x * blockDim.x;
  for (; t < E; t += stride) {
    int s = edges[t];
    int d = edges[E + t];
    int pos = atomicAdd(&cursor[d], 1);
    col[pos] = s;
  }
}

// ================= layer-1 GEMM, LDS-tiled: hs[v] = (x[v] @ W1) * dinv[v] =================
// 165 = 5 * 33 k-chunks. X tile [256 nodes][33 k] stride 33 (bank (t+k)%32, 2-way = free).
// Coalesced global loads (132 B row segments); W chunk broadcast rows from LDS.

__global__ __launch_bounds__(BLK)
void k_gemm1(const float* __restrict__ in, const float* __restrict__ W,
             const float* __restrict__ dinv, float* __restrict__ out, int n) {
  __shared__ float Xl[256 * 33];
  __shared__ float Wl[33 * 64];
  const int t = threadIdx.x;
  const int v0 = blockIdx.x * 256;

  float acc[64];
#pragma unroll
  for (int o = 0; o < 64; ++o) acc[o] = 0.f;

  for (int kc = 0; kc < 165; kc += 33) {
    __syncthreads();
    // X chunk: 256*33 elements, coalesced (33-float contiguous row segments)
    for (int e = t; e < 256 * 33; e += BLK) {
      int row = e / 33;
      int col = e - row * 33;
      int v = v0 + row;
      Xl[e] = (v < n) ? in[(size_t)v * 165 + kc + col] : 0.f;
    }
    // W chunk: 33*64, coalesced
    for (int e = t; e < 33 * 64; e += BLK) {
      Wl[e] = W[kc * 64 + e];
    }
    __syncthreads();

    const float* xr = &Xl[t * 33];
#pragma unroll 3
    for (int k = 0; k < 33; ++k) {
      float xv = xr[k];
      const float* wr = &Wl[k * 64];
#pragma unroll
      for (int o = 0; o < 64; ++o) acc[o] = fmaf(xv, wr[o], acc[o]);
    }
  }

  int v = v0 + t;
  if (v >= n) return;
  float dv = dinv[v];
  float4* orow = (float4*)(out + (size_t)v * 64);
#pragma unroll
  for (int q = 0; q < 16; ++q) {
    float4 r;
    r.x = acc[4 * q + 0] * dv;
    r.y = acc[4 * q + 1] * dv;
    r.z = acc[4 * q + 2] * dv;
    r.w = acc[4 * q + 3] * dv;
    orow[q] = r;
  }
}

// ================= small GEMMs (K%4==0): float4 row loads, W in LDS =================

template<int K, int OUT, bool RELU_IN>
__global__ __launch_bounds__(BLK)
void k_gemm(const float* __restrict__ in, const float* __restrict__ W,
            const float* __restrict__ dinv, float* __restrict__ out, int n) {
  __shared__ float Wl[K * OUT];
  for (int i = threadIdx.x; i < K * OUT; i += BLK) Wl[i] = W[i];
  __syncthreads();

  int v = blockIdx.x * BLK + threadIdx.x;
  if (v >= n) return;

  float acc[OUT];
#pragma unroll
  for (int o = 0; o < OUT; ++o) acc[o] = 0.f;

  const float4* __restrict__ row = (const float4*)(in + (size_t)v * K);
#pragma unroll 2
  for (int k4 = 0; k4 < K / 4; ++k4) {
    float4 xv = row[k4];
    if (RELU_IN) {
      xv.x = fmaxf(xv.x, 0.f); xv.y = fmaxf(xv.y, 0.f);
      xv.z = fmaxf(xv.z, 0.f); xv.w = fmaxf(xv.w, 0.f);
    }
    const float* wr = &Wl[k4 * 4 * OUT];
#pragma unroll
    for (int o = 0; o < OUT; ++o) acc[o] = fmaf(xv.x, wr[o], acc[o]);
#pragma unroll
    for (int o = 0; o < OUT; ++o) acc[o] = fmaf(xv.y, wr[OUT + o], acc[o]);
#pragma unroll
    for (int o = 0; o < OUT; ++o) acc[o] = fmaf(xv.z, wr[2 * OUT + o], acc[o]);
#pragma unroll
    for (int o = 0; o < OUT; ++o) acc[o] = fmaf(xv.w, wr[3 * OUT + o], acc[o]);
  }

  float dv = dinv[v];
  float* orow = out + (size_t)v * OUT;
#pragma unroll
  for (int o = 0; o < OUT; ++o) orow[o] = acc[o] * dv;
}

// ================= CSR gather aggregation =================
// out[v][c] = dinv[v] * ( sum_{s in N(v)} hs[s][c] + hs[v][c] ) + b[c]

__global__ __launch_bounds__(BLK)
void k_gather64(const float* __restrict__ hs, const int* __restrict__ row_start,
                const int* __restrict__ counts, const int* __restrict__ col,
                const float* __restrict__ dinv, const float* __restrict__ b,
                float* __restrict__ out, int n) {
  int wave = threadIdx.x >> 6, lane = threadIdx.x & 63;
  int v = blockIdx.x * 4 + wave;
  if (v >= n) return;
  int beg = row_start[v], cnt = counts[v];
  float acc = hs[(size_t)v * 64 + lane];  // self-loop
  int e = 0;
  for (; e + 3 < cnt; e += 4) {
    int s0 = col[beg + e];
    int s1 = col[beg + e + 1];
    int s2 = col[beg + e + 2];
    int s3 = col[beg + e + 3];
    float a0 = hs[(size_t)s0 * 64 + lane];
    float a1 = hs[(size_t)s1 * 64 + lane];
    float a2 = hs[(size_t)s2 * 64 + lane];
    float a3 = hs[(size_t)s3 * 64 + lane];
    acc += (a0 + a1) + (a2 + a3);
  }
  for (; e < cnt; ++e) acc += hs[(size_t)col[beg + e] * 64 + lane];
  out[(size_t)v * 64 + lane] = fmaf(acc, dinv[v], b[lane]);
}

__global__ __launch_bounds__(BLK)
void k_gather16(const float* __restrict__ hs, const int* __restrict__ row_start,
                const int* __restrict__ counts, const int* __restrict__ col,
                const float* __restrict__ dinv, const float* __restrict__ b,
                float* __restrict__ out, int n) {
  int wave = threadIdx.x >> 6, lane = threadIdx.x & 63;
  int v = blockIdx.x * 4 + wave;
  if (v >= n) return;
  int c = lane & 15, j = lane >> 4;
  int beg = row_start[v], cnt = counts[v];
  float acc = 0.f;
  for (int e = j; e < cnt; e += 4) acc += hs[(size_t)col[beg + e] * 16 + c];
  acc += __shfl_xor(acc, 16);
  acc += __shfl_xor(acc, 32);
  if (j == 0)
    out[(size_t)v * 16 + c] = fmaf(acc + hs[(size_t)v * 16 + c], dinv[v], b[c]);
}

__global__ void k_gather2_lsm(const float* __restrict__ hs, const int* __restrict__ row_start,
                              const int* __restrict__ counts, const int* __restrict__ col,
                              const float* __restrict__ dinv, const float* __restrict__ b,
                              float* __restrict__ out, int n) {
  int v = blockIdx.x * blockDim.x + threadIdx.x;
  if (v >= n) return;
  const float2* hs2 = (const float2*)hs;
  int beg = row_start[v], cnt = counts[v];
  float2 self = hs2[v];
  float a0 = self.x, a1 = self.y;
  for (int e = 0; e < cnt; ++e) {
    float2 m = hs2[col[beg + e]];
    a0 += m.x;
    a1 += m.y;
  }
  float dv = dinv[v];
  a0 = fmaf(a0, dv, b[0]);
  a1 = fmaf(a1, dv, b[1]);
  float m = fmaxf(a0, a1);
  float l = m + logf(expf(a0 - m) + expf(a1 - m));
  out[2 * v] = a0 - l;
  out[2 * v + 1] = a1 - l;
}

// ================= launch =================

static inline int nb(long long total, int cap = 65535) {
  long long b = (total + BLK - 1) / BLK;
  if (b > cap) b = cap;
  if (b < 1) b = 1;
  return (int)b;
}

extern "C" void kernel_launch(void* const* d_in, const int* in_sizes, int n_in,
                              void* d_out, int out_size, void* d_ws, size_t ws_size,
                              hipStream_t stream) {
  const float* x = (const float*)d_in[0];
  const int* edges = (const int*)d_in[1];   // int32
  const float* W1 = (const float*)d_in[2];
  const float* b1 = (const float*)d_in[3];
  const float* W2 = (const float*)d_in[4];
  const float* b2 = (const float*)d_in[5];
  const float* W3 = (const float*)d_in[6];
  const float* b3 = (const float*)d_in[7];
  float* out = (float*)d_out;

  const int N = in_sizes[0] / 165;
  const long long E = in_sizes[1] / 2;

  // workspace layout (keep bufA/bufB 16B aligned)
  char* w = (char*)d_ws;
  int* counts    = (int*)w;               w += (size_t)N * 4;
  int* row_start = (int*)w;               w += (size_t)N * 4;
  int* cursor    = (int*)w;               w += (size_t)N * 4;
  int* blockSums = (int*)w;               w += 1024 * 4;
  int* col       = (int*)w;               w += (size_t)E * 4;
  float* dinv    = (float*)w;             w += (size_t)N * 4;
  float* bufA    = (float*)w;             w += (size_t)N * 64 * 4;
  float* bufB    = (float*)w;             // N*64*4

  const int gN = (N + BLK - 1) / BLK;       // 782 (<=1024 for scan)
  const int gW = (N + 3) / 4;               // wave-per-node grids

  // ---- CSR build + dinv ----
  k_zero<<<gN, BLK, 0, stream>>>(counts, N);
  k_hist<<<nb(E), BLK, 0, stream>>>(edges, E, counts);
  k_scan_block<<<gN, BLK, 0, stream>>>(counts, N, row_start, blockSums);
  k_scan_sums<<<1, 1024, 0, stream>>>(blockSums, gN);
  k_scan_add<<<gN, BLK, 0, stream>>>(row_start, blockSums, cursor, counts, dinv, N);
  k_fill<<<nb(E), BLK, 0, stream>>>(edges, E, cursor, col);

  // ---- layer 1: 165 -> 64 (LDS-tiled) ----
  k_gemm1<<<gN, BLK, 0, stream>>>(x, W1, dinv, bufA, N);
  k_gather64<<<gW, BLK, 0, stream>>>(bufA, row_start, counts, col, dinv, b1, bufB, N);

  // ---- layer 2: 64 -> 16 (relu folded into gemm load) ----
  k_gemm<64, 16, true><<<gN, BLK, 0, stream>>>(bufB, W2, dinv, bufA, N);
  k_gather16<<<gW, BLK, 0, stream>>>(bufA, row_start, counts, col, dinv, b2, bufB, N);

  // ---- layer 3: 16 -> 2 + log-softmax fused into gather ----
  k_gemm<16, 2, true><<<gN, BLK, 0, stream>>>(bufB, W3, dinv, bufA, N);
  k_gather2_lsm<<<gN, BLK, 0, stream>>>(bufA, row_start, counts, col, dinv, b3, out, N);
}

// Round 5
// 1076.876 us; speedup vs baseline: 1.5524x; 1.1017x over previous
//
#include <hip/hip_runtime.h>
#include <cstdint>
#include <math.h>

#define BLK 256

// ================= CSR build =================

__global__ void k_zero(int* __restrict__ p, int n) {
  int i = blockIdx.x * blockDim.x + threadIdx.x;
  if (i < n) p[i] = 0;
}

__global__ void k_hist(const int* __restrict__ edges, long long E, int* __restrict__ counts) {
  long long t = (long long)blockIdx.x * blockDim.x + threadIdx.x;
  long long stride = (long long)gridDim.x * blockDim.x;
  for (; t < E; t += stride) atomicAdd(&counts[edges[E + t]], 1);
}

__global__ __launch_bounds__(BLK)
void k_scan_block(const int* __restrict__ counts, int n,
                  int* __restrict__ row_start, int* __restrict__ blockSums) {
  __shared__ int tmp[BLK];
  int i = blockIdx.x * BLK + threadIdx.x;
  int v = (i < n) ? counts[i] : 0;
  tmp[threadIdx.x] = v;
  __syncthreads();
  for (int off = 1; off < BLK; off <<= 1) {
    int t = (threadIdx.x >= (unsigned)off) ? tmp[threadIdx.x - off] : 0;
    __syncthreads();
    tmp[threadIdx.x] += t;
    __syncthreads();
  }
  if (i < n) row_start[i] = tmp[threadIdx.x] - v;  // exclusive
  if (threadIdx.x == BLK - 1) blockSums[blockIdx.x] = tmp[BLK - 1];
}

__global__ __launch_bounds__(1024)
void k_scan_sums(int* __restrict__ blockSums, int nb) {
  __shared__ int tmp[1024];
  int i = threadIdx.x;
  int v = (i < nb) ? blockSums[i] : 0;
  tmp[i] = v;
  __syncthreads();
  for (int off = 1; off < 1024; off <<= 1) {
    int t = (i >= off) ? tmp[i - off] : 0;
    __syncthreads();
    tmp[i] += t;
    __syncthreads();
  }
  if (i < nb) blockSums[i] = tmp[i] - v;  // exclusive
}

__global__ void k_scan_add(int* __restrict__ row_start, const int* __restrict__ blockSums,
                           int* __restrict__ cursor, const int* __restrict__ counts,
                           float* __restrict__ dinv, int n) {
  int i = blockIdx.x * BLK + threadIdx.x;
  if (i < n) {
    int rs = row_start[i] + blockSums[blockIdx.x];
    row_start[i] = rs;
    cursor[i] = rs;
    dinv[i] = rsqrtf((float)counts[i] + 1.0f);  // +1 self-loop
  }
}

__global__ void k_fill(const int* __restrict__ edges, long long E,
                       int* __restrict__ cursor, int* __restrict__ col) {
  long long t = (long long)blockIdx.x * blockDim.x + threadIdx.x;
  long long stride = (long long)gridDim.x * blockDim.x;
  for (; t < E; t += stride) {
    int s = edges[t];
    int d = edges[E + t];
    int pos = atomicAdd(&cursor[d], 1);
    col[pos] = s;
  }
}

// ================= layer-1 GEMM, register-blocked =================
// tile: 256 nodes x 64 cols per block; thread (tx=t&7 -> 8 cols, ty=t>>3 -> 8 nodes),
// acc[8][8]. X staged TRANSPOSED Xt[k][m] (stride 260: 16B-aligned rows, 2-way read
// banks = free). Per k per thread: 2+2 ds_read_b128 (48 cyc LDS) for 64 FMA (128 cyc
// VALU) -> VALU-bound. K chunked 5x33.

#define XT_STRIDE 260

__global__ __launch_bounds__(BLK)
void k_gemm1(const float* __restrict__ in, const float* __restrict__ W,
             const float* __restrict__ dinv, float* __restrict__ out, int n) {
  __shared__ float Xt[33 * XT_STRIDE];
  __shared__ float Wl[33 * 64];
  const int t = threadIdx.x;
  const int v0 = blockIdx.x * 256;
  const int tx = t & 7;    // col group: cols tx*8 .. tx*8+7
  const int ty = t >> 3;   // node group: nodes ty*8 .. ty*8+7

  float acc[8][8];
#pragma unroll
  for (int i = 0; i < 8; ++i)
#pragma unroll
    for (int j = 0; j < 8; ++j) acc[i][j] = 0.f;

  for (int kc = 0; kc < 165; kc += 33) {
    __syncthreads();
    // stage X chunk transposed: coalesced global read, scattered LDS write (~4-way)
    for (int e = t; e < 256 * 33; e += BLK) {
      int row = e / 33;
      int col = e - row * 33;
      int v = v0 + row;
      Xt[col * XT_STRIDE + row] = (v < n) ? in[(size_t)v * 165 + kc + col] : 0.f;
    }
    // stage W chunk (rows kc..kc+32 contiguous)
    for (int e = t; e < 33 * 64; e += BLK) Wl[e] = W[kc * 64 + e];
    __syncthreads();

    for (int k = 0; k < 33; ++k) {
      const float4 xa = *(const float4*)&Xt[k * XT_STRIDE + ty * 8];
      const float4 xb = *(const float4*)&Xt[k * XT_STRIDE + ty * 8 + 4];
      const float4 wa = *(const float4*)&Wl[k * 64 + tx * 8];
      const float4 wb = *(const float4*)&Wl[k * 64 + tx * 8 + 4];
      const float xm[8] = {xa.x, xa.y, xa.z, xa.w, xb.x, xb.y, xb.z, xb.w};
      const float wc[8] = {wa.x, wa.y, wa.z, wa.w, wb.x, wb.y, wb.z, wb.w};
#pragma unroll
      for (int mi = 0; mi < 8; ++mi)
#pragma unroll
        for (int ci = 0; ci < 8; ++ci)
          acc[mi][ci] = fmaf(xm[mi], wc[ci], acc[mi][ci]);
    }
  }

#pragma unroll
  for (int mi = 0; mi < 8; ++mi) {
    int v = v0 + ty * 8 + mi;
    if (v < n) {
      float dv = dinv[v];
      float4 r0, r1;
      r0.x = acc[mi][0] * dv; r0.y = acc[mi][1] * dv;
      r0.z = acc[mi][2] * dv; r0.w = acc[mi][3] * dv;
      r1.x = acc[mi][4] * dv; r1.y = acc[mi][5] * dv;
      r1.z = acc[mi][6] * dv; r1.w = acc[mi][7] * dv;
      float4* orow = (float4*)(out + (size_t)v * 64 + tx * 8);
      orow[0] = r0;
      orow[1] = r1;
    }
  }
}

// ================= small GEMMs (K%4==0): float4 row loads, W in LDS =================

template<int K, int OUT, bool RELU_IN>
__global__ __launch_bounds__(BLK)
void k_gemm(const float* __restrict__ in, const float* __restrict__ W,
            const float* __restrict__ dinv, float* __restrict__ out, int n) {
  __shared__ float Wl[K * OUT];
  for (int i = threadIdx.x; i < K * OUT; i += BLK) Wl[i] = W[i];
  __syncthreads();

  int v = blockIdx.x * BLK + threadIdx.x;
  if (v >= n) return;

  float acc[OUT];
#pragma unroll
  for (int o = 0; o < OUT; ++o) acc[o] = 0.f;

  const float4* __restrict__ row = (const float4*)(in + (size_t)v * K);
#pragma unroll 2
  for (int k4 = 0; k4 < K / 4; ++k4) {
    float4 xv = row[k4];
    if (RELU_IN) {
      xv.x = fmaxf(xv.x, 0.f); xv.y = fmaxf(xv.y, 0.f);
      xv.z = fmaxf(xv.z, 0.f); xv.w = fmaxf(xv.w, 0.f);
    }
    const float* wr = &Wl[k4 * 4 * OUT];
#pragma unroll
    for (int o = 0; o < OUT; ++o) acc[o] = fmaf(xv.x, wr[o], acc[o]);
#pragma unroll
    for (int o = 0; o < OUT; ++o) acc[o] = fmaf(xv.y, wr[OUT + o], acc[o]);
#pragma unroll
    for (int o = 0; o < OUT; ++o) acc[o] = fmaf(xv.z, wr[2 * OUT + o], acc[o]);
#pragma unroll
    for (int o = 0; o < OUT; ++o) acc[o] = fmaf(xv.w, wr[3 * OUT + o], acc[o]);
  }

  float dv = dinv[v];
  float* orow = out + (size_t)v * OUT;
#pragma unroll
  for (int o = 0; o < OUT; ++o) orow[o] = acc[o] * dv;
}

// ================= CSR gather aggregation =================
// out[v][c] = dinv[v] * ( sum_{s in N(v)} hs[s][c] + hs[v][c] ) + b[c]

__global__ __launch_bounds__(BLK)
void k_gather64(const float* __restrict__ hs, const int* __restrict__ row_start,
                const int* __restrict__ counts, const int* __restrict__ col,
                const float* __restrict__ dinv, const float* __restrict__ b,
                float* __restrict__ out, int n) {
  int wave = threadIdx.x >> 6, lane = threadIdx.x & 63;
  int v = blockIdx.x * 4 + wave;
  if (v >= n) return;
  int beg = row_start[v], cnt = counts[v];
  float acc = hs[(size_t)v * 64 + lane];  // self-loop
  int e = 0;
  for (; e + 3 < cnt; e += 4) {
    int s0 = col[beg + e];
    int s1 = col[beg + e + 1];
    int s2 = col[beg + e + 2];
    int s3 = col[beg + e + 3];
    float a0 = hs[(size_t)s0 * 64 + lane];
    float a1 = hs[(size_t)s1 * 64 + lane];
    float a2 = hs[(size_t)s2 * 64 + lane];
    float a3 = hs[(size_t)s3 * 64 + lane];
    acc += (a0 + a1) + (a2 + a3);
  }
  for (; e < cnt; ++e) acc += hs[(size_t)col[beg + e] * 64 + lane];
  out[(size_t)v * 64 + lane] = fmaf(acc, dinv[v], b[lane]);
}

__global__ __launch_bounds__(BLK)
void k_gather16(const float* __restrict__ hs, const int* __restrict__ row_start,
                const int* __restrict__ counts, const int* __restrict__ col,
                const float* __restrict__ dinv, const float* __restrict__ b,
                float* __restrict__ out, int n) {
  int wave = threadIdx.x >> 6, lane = threadIdx.x & 63;
  int v = blockIdx.x * 4 + wave;
  if (v >= n) return;
  int c = lane & 15, j = lane >> 4;
  int beg = row_start[v], cnt = counts[v];
  float acc = 0.f;
  for (int e = j; e < cnt; e += 4) acc += hs[(size_t)col[beg + e] * 16 + c];
  acc += __shfl_xor(acc, 16);
  acc += __shfl_xor(acc, 32);
  if (j == 0)
    out[(size_t)v * 16 + c] = fmaf(acc + hs[(size_t)v * 16 + c], dinv[v], b[c]);
}

__global__ void k_gather2_lsm(const float* __restrict__ hs, const int* __restrict__ row_start,
                              const int* __restrict__ counts, const int* __restrict__ col,
                              const float* __restrict__ dinv, const float* __restrict__ b,
                              float* __restrict__ out, int n) {
  int v = blockIdx.x * blockDim.x + threadIdx.x;
  if (v >= n) return;
  const float2* hs2 = (const float2*)hs;
  int beg = row_start[v], cnt = counts[v];
  float2 self = hs2[v];
  float a0 = self.x, a1 = self.y;
  for (int e = 0; e < cnt; ++e) {
    float2 m = hs2[col[beg + e]];
    a0 += m.x;
    a1 += m.y;
  }
  float dv = dinv[v];
  a0 = fmaf(a0, dv, b[0]);
  a1 = fmaf(a1, dv, b[1]);
  float m = fmaxf(a0, a1);
  float l = m + logf(expf(a0 - m) + expf(a1 - m));
  out[2 * v] = a0 - l;
  out[2 * v + 1] = a1 - l;
}

// ================= launch =================

static inline int nb(long long total, int cap = 65535) {
  long long b = (total + BLK - 1) / BLK;
  if (b > cap) b = cap;
  if (b < 1) b = 1;
  return (int)b;
}

extern "C" void kernel_launch(void* const* d_in, const int* in_sizes, int n_in,
                              void* d_out, int out_size, void* d_ws, size_t ws_size,
                              hipStream_t stream) {
  const float* x = (const float*)d_in[0];
  const int* edges = (const int*)d_in[1];   // int32
  const float* W1 = (const float*)d_in[2];
  const float* b1 = (const float*)d_in[3];
  const float* W2 = (const float*)d_in[4];
  const float* b2 = (const float*)d_in[5];
  const float* W3 = (const float*)d_in[6];
  const float* b3 = (const float*)d_in[7];
  float* out = (float*)d_out;

  const int N = in_sizes[0] / 165;
  const long long E = in_sizes[1] / 2;

  // workspace layout (keep bufA/bufB 16B aligned)
  char* w = (char*)d_ws;
  int* counts    = (int*)w;               w += (size_t)N * 4;
  int* row_start = (int*)w;               w += (size_t)N * 4;
  int* cursor    = (int*)w;               w += (size_t)N * 4;
  int* blockSums = (int*)w;               w += 1024 * 4;
  int* col       = (int*)w;               w += (size_t)E * 4;
  float* dinv    = (float*)w;             w += (size_t)N * 4;
  float* bufA    = (float*)w;             w += (size_t)N * 64 * 4;
  float* bufB    = (float*)w;             // N*64*4

  const int gN = (N + BLK - 1) / BLK;       // 782 (<=1024 for scan)
  const int gW = (N + 3) / 4;               // wave-per-node grids

  // ---- CSR build + dinv ----
  k_zero<<<gN, BLK, 0, stream>>>(counts, N);
  k_hist<<<nb(E), BLK, 0, stream>>>(edges, E, counts);
  k_scan_block<<<gN, BLK, 0, stream>>>(counts, N, row_start, blockSums);
  k_scan_sums<<<1, 1024, 0, stream>>>(blockSums, gN);
  k_scan_add<<<gN, BLK, 0, stream>>>(row_start, blockSums, cursor, counts, dinv, N);
  k_fill<<<nb(E), BLK, 0, stream>>>(edges, E, cursor, col);

  // ---- layer 1: 165 -> 64 (register-blocked tile) ----
  k_gemm1<<<gN, BLK, 0, stream>>>(x, W1, dinv, bufA, N);
  k_gather64<<<gW, BLK, 0, stream>>>(bufA, row_start, counts, col, dinv, b1, bufB, N);

  // ---- layer 2: 64 -> 16 (relu folded into gemm load) ----
  k_gemm<64, 16, true><<<gN, BLK, 0, stream>>>(bufB, W2, dinv, bufA, N);
  k_gather16<<<gW, BLK, 0, stream>>>(bufA, row_start, counts, col, dinv, b2, bufB, N);

  // ---- layer 3: 16 -> 2 + log-softmax fused into gather ----
  k_gemm<16, 2, true><<<gN, BLK, 0, stream>>>(bufB, W3, dinv, bufA, N);
  k_gather2_lsm<<<gN, BLK, 0, stream>>>(bufA, row_start, counts, col, dinv, b3, out, N);
}

// Round 6
// 868.543 us; speedup vs baseline: 1.9248x; 1.2399x over previous
//
#include <hip/hip_runtime.h>
#include <cstdint>
#include <math.h>

#define BLK 256
#define NBUK_MAX 1024   // buckets = dst>>8 ; N<=262144

// ================= generic =================

__global__ void k_zero(int* __restrict__ p, int n) {
  int i = blockIdx.x * blockDim.x + threadIdx.x;
  if (i < n) p[i] = 0;
}

// ================= CSR build via 2-level binning (no global data atomics) =================

// Phase A: per-block LDS histogram of dst buckets -> global bucket_counts
__global__ __launch_bounds__(BLK)
void k_bcount(const int* __restrict__ edges, long long E, long long chunk, int nbuk,
              int* __restrict__ bucket_counts) {
  __shared__ int hist[NBUK_MAX];
  for (int i = threadIdx.x; i < nbuk; i += BLK) hist[i] = 0;
  __syncthreads();
  long long beg = (long long)blockIdx.x * chunk;
  long long end = beg + chunk < E ? beg + chunk : E;
  for (long long e = beg + threadIdx.x; e < end; e += BLK)
    atomicAdd(&hist[edges[E + e] >> 8], 1);
  __syncthreads();
  for (int i = threadIdx.x; i < nbuk; i += BLK)
    if (hist[i]) atomicAdd(&bucket_counts[i], hist[i]);
}

// Phase B: single-block scan of bucket counts -> bucket_start (exclusive) + cursor + sentinel
__global__ __launch_bounds__(1024)
void k_bscan(const int* __restrict__ bucket_counts, int nbuk,
             int* __restrict__ bucket_start, int* __restrict__ bucket_cursor) {
  __shared__ int tmp[1024];
  int i = threadIdx.x;
  int v = (i < nbuk) ? bucket_counts[i] : 0;
  tmp[i] = v;
  __syncthreads();
  for (int off = 1; off < 1024; off <<= 1) {
    int t = (i >= off) ? tmp[i - off] : 0;
    __syncthreads();
    tmp[i] += t;
    __syncthreads();
  }
  if (i < nbuk) {
    int ex = tmp[i] - v;
    bucket_start[i] = ex;
    bucket_cursor[i] = ex;
  }
  if (i == nbuk - 1) bucket_start[nbuk] = tmp[i];  // sentinel = E
}

// Phase C: partition edges into bucket segments; runs of ~16 packed entries -> full-line writes
__global__ __launch_bounds__(BLK)
void k_bscatter(const int* __restrict__ edges, long long E, long long chunk, int nbuk,
                int* __restrict__ bucket_cursor, int* __restrict__ tmp_out) {
  __shared__ int hist[NBUK_MAX];
  __shared__ int base[NBUK_MAX];
  for (int i = threadIdx.x; i < nbuk; i += BLK) hist[i] = 0;
  __syncthreads();
  long long beg = (long long)blockIdx.x * chunk;
  long long end = beg + chunk < E ? beg + chunk : E;
  for (long long e = beg + threadIdx.x; e < end; e += BLK)
    atomicAdd(&hist[edges[E + e] >> 8], 1);
  __syncthreads();
  for (int i = threadIdx.x; i < nbuk; i += BLK) {
    int c = hist[i];
    base[i] = c ? atomicAdd(&bucket_cursor[i], c) : 0;
    hist[i] = 0;  // reuse as running rank
  }
  __syncthreads();
  for (long long e = beg + threadIdx.x; e < end; e += BLK) {
    int s = edges[e];
    int d = edges[E + e];
    int b = d >> 8;
    int r = atomicAdd(&hist[b], 1);
    tmp_out[base[b] + r] = (s << 8) | (d & 255);  // s < 2^18 -> packed < 2^26
  }
}

// Phase D: one block per bucket; exact per-node CSR inside the bucket segment
__global__ __launch_bounds__(BLK)
void k_bfinal(const int* __restrict__ tmp_in, const int* __restrict__ bucket_start, int n,
              int* __restrict__ row_start, int* __restrict__ counts,
              float* __restrict__ dinv, int* __restrict__ col) {
  __shared__ int cnt[256];
  __shared__ int scan[256];
  __shared__ int cur[256];
  const int b = blockIdx.x, t = threadIdx.x;
  const int seg0 = bucket_start[b], seg1 = bucket_start[b + 1];
  cnt[t] = 0;
  __syncthreads();
  for (int i = seg0 + t; i < seg1; i += BLK) atomicAdd(&cnt[tmp_in[i] & 255], 1);
  __syncthreads();
  int v0 = cnt[t];
  scan[t] = v0;
  __syncthreads();
  for (int off = 1; off < 256; off <<= 1) {
    int x = (t >= off) ? scan[t - off] : 0;
    __syncthreads();
    scan[t] += x;
    __syncthreads();
  }
  int loff = scan[t] - v0;  // exclusive local offset
  int v = b * 256 + t;
  if (v < n) {
    row_start[v] = seg0 + loff;
    counts[v] = v0;
    dinv[v] = rsqrtf((float)v0 + 1.0f);  // +1 self-loop
  }
  cur[t] = loff;
  __syncthreads();
  for (int i = seg0 + t; i < seg1; i += BLK) {
    int p = tmp_in[i];
    int r = atomicAdd(&cur[p & 255], 1);
    col[seg0 + r] = p >> 8;
  }
}

// ================= layer-1 GEMM, register-blocked =================

#define XT_STRIDE 260

__global__ __launch_bounds__(BLK)
void k_gemm1(const float* __restrict__ in, const float* __restrict__ W,
             const float* __restrict__ dinv, float* __restrict__ out, int n) {
  __shared__ float Xt[33 * XT_STRIDE];
  __shared__ float Wl[33 * 64];
  const int t = threadIdx.x;
  const int v0 = blockIdx.x * 256;
  const int tx = t & 7;
  const int ty = t >> 3;

  float acc[8][8];
#pragma unroll
  for (int i = 0; i < 8; ++i)
#pragma unroll
    for (int j = 0; j < 8; ++j) acc[i][j] = 0.f;

  for (int kc = 0; kc < 165; kc += 33) {
    __syncthreads();
    for (int e = t; e < 256 * 33; e += BLK) {
      int row = e / 33;
      int col = e - row * 33;
      int v = v0 + row;
      Xt[col * XT_STRIDE + row] = (v < n) ? in[(size_t)v * 165 + kc + col] : 0.f;
    }
    for (int e = t; e < 33 * 64; e += BLK) Wl[e] = W[kc * 64 + e];
    __syncthreads();

    for (int k = 0; k < 33; ++k) {
      const float4 xa = *(const float4*)&Xt[k * XT_STRIDE + ty * 8];
      const float4 xb = *(const float4*)&Xt[k * XT_STRIDE + ty * 8 + 4];
      const float4 wa = *(const float4*)&Wl[k * 64 + tx * 8];
      const float4 wb = *(const float4*)&Wl[k * 64 + tx * 8 + 4];
      const float xm[8] = {xa.x, xa.y, xa.z, xa.w, xb.x, xb.y, xb.z, xb.w};
      const float wc[8] = {wa.x, wa.y, wa.z, wa.w, wb.x, wb.y, wb.z, wb.w};
#pragma unroll
      for (int mi = 0; mi < 8; ++mi)
#pragma unroll
        for (int ci = 0; ci < 8; ++ci)
          acc[mi][ci] = fmaf(xm[mi], wc[ci], acc[mi][ci]);
    }
  }

#pragma unroll
  for (int mi = 0; mi < 8; ++mi) {
    int v = v0 + ty * 8 + mi;
    if (v < n) {
      float dv = dinv[v];
      float4 r0, r1;
      r0.x = acc[mi][0] * dv; r0.y = acc[mi][1] * dv;
      r0.z = acc[mi][2] * dv; r0.w = acc[mi][3] * dv;
      r1.x = acc[mi][4] * dv; r1.y = acc[mi][5] * dv;
      r1.z = acc[mi][6] * dv; r1.w = acc[mi][7] * dv;
      float4* orow = (float4*)(out + (size_t)v * 64 + tx * 8);
      orow[0] = r0;
      orow[1] = r1;
    }
  }
}

// ================= small GEMMs (K%4==0): float4 row loads, W in LDS =================

template<int K, int OUT, bool RELU_IN>
__global__ __launch_bounds__(BLK)
void k_gemm(const float* __restrict__ in, const float* __restrict__ W,
            const float* __restrict__ dinv, float* __restrict__ out, int n) {
  __shared__ float Wl[K * OUT];
  for (int i = threadIdx.x; i < K * OUT; i += BLK) Wl[i] = W[i];
  __syncthreads();

  int v = blockIdx.x * BLK + threadIdx.x;
  if (v >= n) return;

  float acc[OUT];
#pragma unroll
  for (int o = 0; o < OUT; ++o) acc[o] = 0.f;

  const float4* __restrict__ row = (const float4*)(in + (size_t)v * K);
#pragma unroll 2
  for (int k4 = 0; k4 < K / 4; ++k4) {
    float4 xv = row[k4];
    if (RELU_IN) {
      xv.x = fmaxf(xv.x, 0.f); xv.y = fmaxf(xv.y, 0.f);
      xv.z = fmaxf(xv.z, 0.f); xv.w = fmaxf(xv.w, 0.f);
    }
    const float* wr = &Wl[k4 * 4 * OUT];
#pragma unroll
    for (int o = 0; o < OUT; ++o) acc[o] = fmaf(xv.x, wr[o], acc[o]);
#pragma unroll
    for (int o = 0; o < OUT; ++o) acc[o] = fmaf(xv.y, wr[OUT + o], acc[o]);
#pragma unroll
    for (int o = 0; o < OUT; ++o) acc[o] = fmaf(xv.z, wr[2 * OUT + o], acc[o]);
#pragma unroll
    for (int o = 0; o < OUT; ++o) acc[o] = fmaf(xv.w, wr[3 * OUT + o], acc[o]);
  }

  float dv = dinv[v];
  float* orow = out + (size_t)v * OUT;
#pragma unroll
  for (int o = 0; o < OUT; ++o) orow[o] = acc[o] * dv;
}

// ================= CSR gather aggregation =================

__global__ __launch_bounds__(BLK)
void k_gather64(const float* __restrict__ hs, const int* __restrict__ row_start,
                const int* __restrict__ counts, const int* __restrict__ col,
                const float* __restrict__ dinv, const float* __restrict__ b,
                float* __restrict__ out, int n) {
  int wave = threadIdx.x >> 6, lane = threadIdx.x & 63;
  int v = blockIdx.x * 4 + wave;
  if (v >= n) return;
  int beg = row_start[v], cnt = counts[v];
  float acc = hs[(size_t)v * 64 + lane];  // self-loop
  int e = 0;
  for (; e + 3 < cnt; e += 4) {
    int s0 = col[beg + e];
    int s1 = col[beg + e + 1];
    int s2 = col[beg + e + 2];
    int s3 = col[beg + e + 3];
    float a0 = hs[(size_t)s0 * 64 + lane];
    float a1 = hs[(size_t)s1 * 64 + lane];
    float a2 = hs[(size_t)s2 * 64 + lane];
    float a3 = hs[(size_t)s3 * 64 + lane];
    acc += (a0 + a1) + (a2 + a3);
  }
  for (; e < cnt; ++e) acc += hs[(size_t)col[beg + e] * 64 + lane];
  out[(size_t)v * 64 + lane] = fmaf(acc, dinv[v], b[lane]);
}

__global__ __launch_bounds__(BLK)
void k_gather16(const float* __restrict__ hs, const int* __restrict__ row_start,
                const int* __restrict__ counts, const int* __restrict__ col,
                const float* __restrict__ dinv, const float* __restrict__ b,
                float* __restrict__ out, int n) {
  int wave = threadIdx.x >> 6, lane = threadIdx.x & 63;
  int v = blockIdx.x * 4 + wave;
  if (v >= n) return;
  int c = lane & 15, j = lane >> 4;
  int beg = row_start[v], cnt = counts[v];
  float acc = 0.f;
  for (int e = j; e < cnt; e += 4) acc += hs[(size_t)col[beg + e] * 16 + c];
  acc += __shfl_xor(acc, 16);
  acc += __shfl_xor(acc, 32);
  if (j == 0)
    out[(size_t)v * 16 + c] = fmaf(acc + hs[(size_t)v * 16 + c], dinv[v], b[c]);
}

__global__ void k_gather2_lsm(const float* __restrict__ hs, const int* __restrict__ row_start,
                              const int* __restrict__ counts, const int* __restrict__ col,
                              const float* __restrict__ dinv, const float* __restrict__ b,
                              float* __restrict__ out, int n) {
  int v = blockIdx.x * blockDim.x + threadIdx.x;
  if (v >= n) return;
  const float2* hs2 = (const float2*)hs;
  int beg = row_start[v], cnt = counts[v];
  float2 self = hs2[v];
  float a0 = self.x, a1 = self.y;
  for (int e = 0; e < cnt; ++e) {
    float2 m = hs2[col[beg + e]];
    a0 += m.x;
    a1 += m.y;
  }
  float dv = dinv[v];
  a0 = fmaf(a0, dv, b[0]);
  a1 = fmaf(a1, dv, b[1]);
  float m = fmaxf(a0, a1);
  float l = m + logf(expf(a0 - m) + expf(a1 - m));
  out[2 * v] = a0 - l;
  out[2 * v + 1] = a1 - l;
}

// ================= launch =================

extern "C" void kernel_launch(void* const* d_in, const int* in_sizes, int n_in,
                              void* d_out, int out_size, void* d_ws, size_t ws_size,
                              hipStream_t stream) {
  const float* x = (const float*)d_in[0];
  const int* edges = (const int*)d_in[1];   // int32
  const float* W1 = (const float*)d_in[2];
  const float* b1 = (const float*)d_in[3];
  const float* W2 = (const float*)d_in[4];
  const float* b2 = (const float*)d_in[5];
  const float* W3 = (const float*)d_in[6];
  const float* b3 = (const float*)d_in[7];
  float* out = (float*)d_out;

  const int N = in_sizes[0] / 165;
  const long long E = in_sizes[1] / 2;
  const int nbuk = (N + 255) >> 8;          // 782

  // workspace layout (16B-aligned chunks)
  char* w = (char*)d_ws;
  int* counts        = (int*)w;  w += (size_t)N * 4;
  int* row_start     = (int*)w;  w += (size_t)N * 4;
  float* dinv        = (float*)w; w += (size_t)N * 4;
  int* bucket_counts = (int*)w;  w += (NBUK_MAX + 4) * 4;
  int* bucket_start  = (int*)w;  w += (NBUK_MAX + 4) * 4;
  int* bucket_cursor = (int*)w;  w += (NBUK_MAX + 4) * 4;
  int* col           = (int*)w;  w += (size_t)E * 4;
  float* bufA        = (float*)w; w += (size_t)N * 64 * 4;
  float* bufB        = (float*)w;  // N*64*4
  int* tmp = (int*)bufA;           // aliases bufA: used only before k_gemm1 writes it

  const int gN = (N + BLK - 1) / BLK;
  const int gW = (N + 3) / 4;
  const int NB_PART = 256;
  const long long chunk = (E + NB_PART - 1) / NB_PART;

  // ---- CSR build (binning) + dinv ----
  k_zero<<<(nbuk + BLK - 1) / BLK, BLK, 0, stream>>>(bucket_counts, nbuk);
  k_bcount<<<NB_PART, BLK, 0, stream>>>(edges, E, chunk, nbuk, bucket_counts);
  k_bscan<<<1, 1024, 0, stream>>>(bucket_counts, nbuk, bucket_start, bucket_cursor);
  k_bscatter<<<NB_PART, BLK, 0, stream>>>(edges, E, chunk, nbuk, bucket_cursor, tmp);
  k_bfinal<<<nbuk, BLK, 0, stream>>>(tmp, bucket_start, N, row_start, counts, dinv, col);

  // ---- layer 1: 165 -> 64 (register-blocked tile) ----
  k_gemm1<<<gN, BLK, 0, stream>>>(x, W1, dinv, bufA, N);
  k_gather64<<<gW, BLK, 0, stream>>>(bufA, row_start, counts, col, dinv, b1, bufB, N);

  // ---- layer 2: 64 -> 16 (relu folded into gemm load) ----
  k_gemm<64, 16, true><<<gN, BLK, 0, stream>>>(bufB, W2, dinv, bufA, N);
  k_gather16<<<gW, BLK, 0, stream>>>(bufA, row_start, counts, col, dinv, b2, bufB, N);

  // ---- layer 3: 16 -> 2 + log-softmax fused into gather ----
  k_gemm<16, 2, true><<<gN, BLK, 0, stream>>>(bufB, W3, dinv, bufA, N);
  k_gather2_lsm<<<gN, BLK, 0, stream>>>(bufA, row_start, counts, col, dinv, b3, out, N);
}

// Round 7
// 765.542 us; speedup vs baseline: 2.1838x; 1.1345x over previous
//
#include <hip/hip_runtime.h>
#include <cstdint>
#include <math.h>

#define BLK 256
#define NBUK_MAX 1024   // buckets = dst>>8 ; N<=262144

// ================= generic =================

__global__ void k_zero(int* __restrict__ p, int n) {
  int i = blockIdx.x * blockDim.x + threadIdx.x;
  if (i < n) p[i] = 0;
}

// ================= CSR build via 2-level binning (no global data atomics) =================

__global__ __launch_bounds__(BLK)
void k_bcount(const int* __restrict__ edges, long long E, long long chunk, int nbuk,
              int* __restrict__ bucket_counts) {
  __shared__ int hist[NBUK_MAX];
  for (int i = threadIdx.x; i < nbuk; i += BLK) hist[i] = 0;
  __syncthreads();
  long long beg = (long long)blockIdx.x * chunk;
  long long end = beg + chunk < E ? beg + chunk : E;
  for (long long e = beg + threadIdx.x; e < end; e += BLK)
    atomicAdd(&hist[edges[E + e] >> 8], 1);
  __syncthreads();
  for (int i = threadIdx.x; i < nbuk; i += BLK)
    if (hist[i]) atomicAdd(&bucket_counts[i], hist[i]);
}

__global__ __launch_bounds__(1024)
void k_bscan(const int* __restrict__ bucket_counts, int nbuk,
             int* __restrict__ bucket_start, int* __restrict__ bucket_cursor) {
  __shared__ int tmp[1024];
  int i = threadIdx.x;
  int v = (i < nbuk) ? bucket_counts[i] : 0;
  tmp[i] = v;
  __syncthreads();
  for (int off = 1; off < 1024; off <<= 1) {
    int t = (i >= off) ? tmp[i - off] : 0;
    __syncthreads();
    tmp[i] += t;
    __syncthreads();
  }
  if (i < nbuk) {
    int ex = tmp[i] - v;
    bucket_start[i] = ex;
    bucket_cursor[i] = ex;
  }
  if (i == nbuk - 1) bucket_start[nbuk] = tmp[i];  // sentinel = E
}

__global__ __launch_bounds__(BLK)
void k_bscatter(const int* __restrict__ edges, long long E, long long chunk, int nbuk,
                int* __restrict__ bucket_cursor, int* __restrict__ tmp_out) {
  __shared__ int hist[NBUK_MAX];
  __shared__ int base[NBUK_MAX];
  for (int i = threadIdx.x; i < nbuk; i += BLK) hist[i] = 0;
  __syncthreads();
  long long beg = (long long)blockIdx.x * chunk;
  long long end = beg + chunk < E ? beg + chunk : E;
  for (long long e = beg + threadIdx.x; e < end; e += BLK)
    atomicAdd(&hist[edges[E + e] >> 8], 1);
  __syncthreads();
  for (int i = threadIdx.x; i < nbuk; i += BLK) {
    int c = hist[i];
    base[i] = c ? atomicAdd(&bucket_cursor[i], c) : 0;
    hist[i] = 0;  // reuse as running rank
  }
  __syncthreads();
  for (long long e = beg + threadIdx.x; e < end; e += BLK) {
    int s = edges[e];
    int d = edges[E + e];
    int b = d >> 8;
    int r = atomicAdd(&hist[b], 1);
    tmp_out[base[b] + r] = (s << 8) | (d & 255);  // s < 2^18 -> packed < 2^26
  }
}

__global__ __launch_bounds__(BLK)
void k_bfinal(const int* __restrict__ tmp_in, const int* __restrict__ bucket_start, int n,
              int* __restrict__ row_start, int* __restrict__ counts,
              float* __restrict__ dinv, int* __restrict__ col) {
  __shared__ int cnt[256];
  __shared__ int scan[256];
  __shared__ int cur[256];
  const int b = blockIdx.x, t = threadIdx.x;
  const int seg0 = bucket_start[b], seg1 = bucket_start[b + 1];
  cnt[t] = 0;
  __syncthreads();
  for (int i = seg0 + t; i < seg1; i += BLK) atomicAdd(&cnt[tmp_in[i] & 255], 1);
  __syncthreads();
  int v0 = cnt[t];
  scan[t] = v0;
  __syncthreads();
  for (int off = 1; off < 256; off <<= 1) {
    int x = (t >= off) ? scan[t - off] : 0;
    __syncthreads();
    scan[t] += x;
    __syncthreads();
  }
  int loff = scan[t] - v0;  // exclusive local offset
  int v = b * 256 + t;
  if (v < n) {
    row_start[v] = seg0 + loff;
    counts[v] = v0;
    dinv[v] = rsqrtf((float)v0 + 1.0f);  // +1 self-loop
  }
  cur[t] = loff;
  __syncthreads();
  for (int i = seg0 + t; i < seg1; i += BLK) {
    int p = tmp_in[i];
    int r = atomicAdd(&cur[p & 255], 1);
    col[seg0 + r] = p >> 8;
  }
}

// ================= layer-1 GEMM, register-blocked + pipelined staging =================
// Per 33-wide K chunk: 33 X elems + 9 W elems loaded into REGISTERS as one
// independent batch (33 outstanding loads/wave, not 1), chunk k+1 prefetched
// while computing chunk k from LDS. Xt transposed stride 260 (b128-aligned reads).

#define XSTR 260

__global__ __launch_bounds__(BLK)
void k_gemm1(const float* __restrict__ in, const float* __restrict__ W,
             const float* __restrict__ dinv, float* __restrict__ out, int n) {
  __shared__ float Xt[33 * XSTR];
  __shared__ float Wl[33 * 64];
  const int t = threadIdx.x;
  const int v0 = blockIdx.x * 256;
  const int tx = t & 7;
  const int ty = t >> 3;

  float xf[33];
  float wf[9];

  float acc[8][8];
#pragma unroll
  for (int i = 0; i < 8; ++i)
#pragma unroll
    for (int j = 0; j < 8; ++j) acc[i][j] = 0.f;

  // ---- load chunk 0 into registers (batched, independent) ----
#pragma unroll
  for (int i = 0; i < 33; ++i) {
    int e = t + i * 256;
    int row = e / 33, c = e - row * 33;
    int v = v0 + row;
    xf[i] = (v < n) ? in[(size_t)v * 165 + c] : 0.f;
  }
#pragma unroll
  for (int i = 0; i < 9; ++i) {
    int e = t + i * 256;
    wf[i] = (e < 2112) ? W[e] : 0.f;
  }

  for (int kc = 0; kc < 165; kc += 33) {
    __syncthreads();  // previous chunk's LDS consumers done
    // ---- registers -> LDS (vmcnt wait happens here, once per chunk) ----
#pragma unroll
    for (int i = 0; i < 33; ++i) {
      int e = t + i * 256;
      int row = e / 33, c = e - row * 33;
      Xt[c * XSTR + row] = xf[i];
    }
#pragma unroll
    for (int i = 0; i < 9; ++i) {
      int e = t + i * 256;
      if (e < 2112) Wl[e] = wf[i];
    }
    __syncthreads();

    // ---- prefetch next chunk into registers (no wait; overlaps compute) ----
    if (kc + 33 < 165) {
      int kn = kc + 33;
#pragma unroll
      for (int i = 0; i < 33; ++i) {
        int e = t + i * 256;
        int row = e / 33, c = e - row * 33;
        int v = v0 + row;
        xf[i] = (v < n) ? in[(size_t)v * 165 + kn + c] : 0.f;
      }
#pragma unroll
      for (int i = 0; i < 9; ++i) {
        int e = t + i * 256;
        wf[i] = (e < 2112) ? W[kn * 64 + e] : 0.f;
      }
    }

    // ---- compute current chunk from LDS ----
    for (int k = 0; k < 33; ++k) {
      const float4 xa = *(const float4*)&Xt[k * XSTR + ty * 8];
      const float4 xb = *(const float4*)&Xt[k * XSTR + ty * 8 + 4];
      const float4 wa = *(const float4*)&Wl[k * 64 + tx * 8];
      const float4 wb = *(const float4*)&Wl[k * 64 + tx * 8 + 4];
      const float xm[8] = {xa.x, xa.y, xa.z, xa.w, xb.x, xb.y, xb.z, xb.w};
      const float wc[8] = {wa.x, wa.y, wa.z, wa.w, wb.x, wb.y, wb.z, wb.w};
#pragma unroll
      for (int mi = 0; mi < 8; ++mi)
#pragma unroll
        for (int ci = 0; ci < 8; ++ci)
          acc[mi][ci] = fmaf(xm[mi], wc[ci], acc[mi][ci]);
    }
  }

#pragma unroll
  for (int mi = 0; mi < 8; ++mi) {
    int v = v0 + ty * 8 + mi;
    if (v < n) {
      float dv = dinv[v];
      float4 r0, r1;
      r0.x = acc[mi][0] * dv; r0.y = acc[mi][1] * dv;
      r0.z = acc[mi][2] * dv; r0.w = acc[mi][3] * dv;
      r1.x = acc[mi][4] * dv; r1.y = acc[mi][5] * dv;
      r1.z = acc[mi][6] * dv; r1.w = acc[mi][7] * dv;
      float4* orow = (float4*)(out + (size_t)v * 64 + tx * 8);
      orow[0] = r0;
      orow[1] = r1;
    }
  }
}

// ================= small GEMMs (K%4==0): float4 row loads, W in LDS =================

template<int K, int OUT, bool RELU_IN>
__global__ __launch_bounds__(BLK)
void k_gemm(const float* __restrict__ in, const float* __restrict__ W,
            const float* __restrict__ dinv, float* __restrict__ out, int n) {
  __shared__ float Wl[K * OUT];
  for (int i = threadIdx.x; i < K * OUT; i += BLK) Wl[i] = W[i];
  __syncthreads();

  int v = blockIdx.x * BLK + threadIdx.x;
  if (v >= n) return;

  float acc[OUT];
#pragma unroll
  for (int o = 0; o < OUT; ++o) acc[o] = 0.f;

  const float4* __restrict__ row = (const float4*)(in + (size_t)v * K);
#pragma unroll 2
  for (int k4 = 0; k4 < K / 4; ++k4) {
    float4 xv = row[k4];
    if (RELU_IN) {
      xv.x = fmaxf(xv.x, 0.f); xv.y = fmaxf(xv.y, 0.f);
      xv.z = fmaxf(xv.z, 0.f); xv.w = fmaxf(xv.w, 0.f);
    }
    const float* wr = &Wl[k4 * 4 * OUT];
#pragma unroll
    for (int o = 0; o < OUT; ++o) acc[o] = fmaf(xv.x, wr[o], acc[o]);
#pragma unroll
    for (int o = 0; o < OUT; ++o) acc[o] = fmaf(xv.y, wr[OUT + o], acc[o]);
#pragma unroll
    for (int o = 0; o < OUT; ++o) acc[o] = fmaf(xv.z, wr[2 * OUT + o], acc[o]);
#pragma unroll
    for (int o = 0; o < OUT; ++o) acc[o] = fmaf(xv.w, wr[3 * OUT + o], acc[o]);
  }

  float dv = dinv[v];
  float* orow = out + (size_t)v * OUT;
#pragma unroll
  for (int o = 0; o < OUT; ++o) orow[o] = acc[o] * dv;
}

// ================= CSR gather aggregation =================

__global__ __launch_bounds__(BLK)
void k_gather64(const float* __restrict__ hs, const int* __restrict__ row_start,
                const int* __restrict__ counts, const int* __restrict__ col,
                const float* __restrict__ dinv, const float* __restrict__ b,
                float* __restrict__ out, int n) {
  int wave = threadIdx.x >> 6, lane = threadIdx.x & 63;
  int v = blockIdx.x * 4 + wave;
  if (v >= n) return;
  int beg = row_start[v], cnt = counts[v];
  float acc = hs[(size_t)v * 64 + lane];  // self-loop
  int e = 0;
  for (; e + 3 < cnt; e += 4) {
    int s0 = col[beg + e];
    int s1 = col[beg + e + 1];
    int s2 = col[beg + e + 2];
    int s3 = col[beg + e + 3];
    float a0 = hs[(size_t)s0 * 64 + lane];
    float a1 = hs[(size_t)s1 * 64 + lane];
    float a2 = hs[(size_t)s2 * 64 + lane];
    float a3 = hs[(size_t)s3 * 64 + lane];
    acc += (a0 + a1) + (a2 + a3);
  }
  for (; e < cnt; ++e) acc += hs[(size_t)col[beg + e] * 64 + lane];
  out[(size_t)v * 64 + lane] = fmaf(acc, dinv[v], b[lane]);
}

__global__ __launch_bounds__(BLK)
void k_gather16(const float* __restrict__ hs, const int* __restrict__ row_start,
                const int* __restrict__ counts, const int* __restrict__ col,
                const float* __restrict__ dinv, const float* __restrict__ b,
                float* __restrict__ out, int n) {
  int wave = threadIdx.x >> 6, lane = threadIdx.x & 63;
  int v = blockIdx.x * 4 + wave;
  if (v >= n) return;
  int c = lane & 15, j = lane >> 4;
  int beg = row_start[v], cnt = counts[v];
  float acc = 0.f;
  for (int e = j; e < cnt; e += 4) acc += hs[(size_t)col[beg + e] * 16 + c];
  acc += __shfl_xor(acc, 16);
  acc += __shfl_xor(acc, 32);
  if (j == 0)
    out[(size_t)v * 16 + c] = fmaf(acc + hs[(size_t)v * 16 + c], dinv[v], b[c]);
}

__global__ void k_gather2_lsm(const float* __restrict__ hs, const int* __restrict__ row_start,
                              const int* __restrict__ counts, const int* __restrict__ col,
                              const float* __restrict__ dinv, const float* __restrict__ b,
                              float* __restrict__ out, int n) {
  int v = blockIdx.x * blockDim.x + threadIdx.x;
  if (v >= n) return;
  const float2* hs2 = (const float2*)hs;
  int beg = row_start[v], cnt = counts[v];
  float2 self = hs2[v];
  float a0 = self.x, a1 = self.y;
  for (int e = 0; e < cnt; ++e) {
    float2 m = hs2[col[beg + e]];
    a0 += m.x;
    a1 += m.y;
  }
  float dv = dinv[v];
  a0 = fmaf(a0, dv, b[0]);
  a1 = fmaf(a1, dv, b[1]);
  float m = fmaxf(a0, a1);
  float l = m + logf(expf(a0 - m) + expf(a1 - m));
  out[2 * v] = a0 - l;
  out[2 * v + 1] = a1 - l;
}

// ================= launch =================

extern "C" void kernel_launch(void* const* d_in, const int* in_sizes, int n_in,
                              void* d_out, int out_size, void* d_ws, size_t ws_size,
                              hipStream_t stream) {
  const float* x = (const float*)d_in[0];
  const int* edges = (const int*)d_in[1];   // int32
  const float* W1 = (const float*)d_in[2];
  const float* b1 = (const float*)d_in[3];
  const float* W2 = (const float*)d_in[4];
  const float* b2 = (const float*)d_in[5];
  const float* W3 = (const float*)d_in[6];
  const float* b3 = (const float*)d_in[7];
  float* out = (float*)d_out;

  const int N = in_sizes[0] / 165;
  const long long E = in_sizes[1] / 2;
  const int nbuk = (N + 255) >> 8;          // 782

  // workspace layout (16B-aligned chunks)
  char* w = (char*)d_ws;
  int* counts        = (int*)w;  w += (size_t)N * 4;
  int* row_start     = (int*)w;  w += (size_t)N * 4;
  float* dinv        = (float*)w; w += (size_t)N * 4;
  int* bucket_counts = (int*)w;  w += (NBUK_MAX + 4) * 4;
  int* bucket_start  = (int*)w;  w += (NBUK_MAX + 4) * 4;
  int* bucket_cursor = (int*)w;  w += (NBUK_MAX + 4) * 4;
  int* col           = (int*)w;  w += (size_t)E * 4;
  float* bufA        = (float*)w; w += (size_t)N * 64 * 4;
  float* bufB        = (float*)w;  // N*64*4
  int* tmp = (int*)bufA;           // aliases bufA: used only before k_gemm1 writes it

  const int gN = (N + BLK - 1) / BLK;
  const int gW = (N + 3) / 4;
  const int NB_PART = 256;
  const long long chunk = (E + NB_PART - 1) / NB_PART;

  // ---- CSR build (binning) + dinv ----
  k_zero<<<(nbuk + BLK - 1) / BLK, BLK, 0, stream>>>(bucket_counts, nbuk);
  k_bcount<<<NB_PART, BLK, 0, stream>>>(edges, E, chunk, nbuk, bucket_counts);
  k_bscan<<<1, 1024, 0, stream>>>(bucket_counts, nbuk, bucket_start, bucket_cursor);
  k_bscatter<<<NB_PART, BLK, 0, stream>>>(edges, E, chunk, nbuk, bucket_cursor, tmp);
  k_bfinal<<<nbuk, BLK, 0, stream>>>(tmp, bucket_start, N, row_start, counts, dinv, col);

  // ---- layer 1: 165 -> 64 (register-blocked, pipelined staging) ----
  k_gemm1<<<gN, BLK, 0, stream>>>(x, W1, dinv, bufA, N);
  k_gather64<<<gW, BLK, 0, stream>>>(bufA, row_start, counts, col, dinv, b1, bufB, N);

  // ---- layer 2: 64 -> 16 (relu folded into gemm load) ----
  k_gemm<64, 16, true><<<gN, BLK, 0, stream>>>(bufB, W2, dinv, bufA, N);
  k_gather16<<<gW, BLK, 0, stream>>>(bufA, row_start, counts, col, dinv, b2, bufB, N);

  // ---- layer 3: 16 -> 2 + log-softmax fused into gather ----
  k_gemm<16, 2, true><<<gN, BLK, 0, stream>>>(bufB, W3, dinv, bufA, N);
  k_gather2_lsm<<<gN, BLK, 0, stream>>>(bufA, row_start, counts, col, dinv, b3, out, N);
}

// Round 8
// 676.777 us; speedup vs baseline: 2.4702x; 1.1312x over previous
//
#include <hip/hip_runtime.h>
#include <cstdint>
#include <math.h>

#define BLK 256
#define NBUK_MAX 1024   // buckets = dst>>8 ; N<=262144

// ---- bf16 pack/unpack helpers ----
__device__ __forceinline__ float bf_lo(unsigned p) { return __uint_as_float(p << 16); }
__device__ __forceinline__ float bf_hi(unsigned p) { return __uint_as_float(p & 0xffff0000u); }
__device__ __forceinline__ unsigned pack2(float a, float b) {
  unsigned ua = __float_as_uint(a), ub = __float_as_uint(b);
  ua = (ua + 0x7fffu + ((ua >> 16) & 1u)) >> 16;        // rne
  ub = (ub + 0x7fffu + ((ub >> 16) & 1u)) >> 16;
  return (ua & 0xffffu) | (ub << 16);
}

// ================= generic =================

__global__ void k_zero(int* __restrict__ p, int n) {
  int i = blockIdx.x * blockDim.x + threadIdx.x;
  if (i < n) p[i] = 0;
}

// ================= CSR build via 2-level binning (no global data atomics) =================

__global__ __launch_bounds__(BLK)
void k_bcount(const int* __restrict__ edges, long long E, long long chunk, int nbuk,
              int* __restrict__ bucket_counts) {
  __shared__ int hist[NBUK_MAX];
  for (int i = threadIdx.x; i < nbuk; i += BLK) hist[i] = 0;
  __syncthreads();
  long long beg = (long long)blockIdx.x * chunk;
  long long end = beg + chunk < E ? beg + chunk : E;
  for (long long e = beg + threadIdx.x; e < end; e += BLK)
    atomicAdd(&hist[edges[E + e] >> 8], 1);
  __syncthreads();
  for (int i = threadIdx.x; i < nbuk; i += BLK)
    if (hist[i]) atomicAdd(&bucket_counts[i], hist[i]);
}

__global__ __launch_bounds__(1024)
void k_bscan(const int* __restrict__ bucket_counts, int nbuk,
             int* __restrict__ bucket_start, int* __restrict__ bucket_cursor) {
  __shared__ int tmp[1024];
  int i = threadIdx.x;
  int v = (i < nbuk) ? bucket_counts[i] : 0;
  tmp[i] = v;
  __syncthreads();
  for (int off = 1; off < 1024; off <<= 1) {
    int t = (i >= off) ? tmp[i - off] : 0;
    __syncthreads();
    tmp[i] += t;
    __syncthreads();
  }
  if (i < nbuk) {
    int ex = tmp[i] - v;
    bucket_start[i] = ex;
    bucket_cursor[i] = ex;
  }
  if (i == nbuk - 1) bucket_start[nbuk] = tmp[i];  // sentinel = E
}

__global__ __launch_bounds__(BLK)
void k_bscatter(const int* __restrict__ edges, long long E, long long chunk, int nbuk,
                int* __restrict__ bucket_cursor, int* __restrict__ tmp_out) {
  __shared__ int hist[NBUK_MAX];
  __shared__ int base[NBUK_MAX];
  for (int i = threadIdx.x; i < nbuk; i += BLK) hist[i] = 0;
  __syncthreads();
  long long beg = (long long)blockIdx.x * chunk;
  long long end = beg + chunk < E ? beg + chunk : E;
  for (long long e = beg + threadIdx.x; e < end; e += BLK)
    atomicAdd(&hist[edges[E + e] >> 8], 1);
  __syncthreads();
  for (int i = threadIdx.x; i < nbuk; i += BLK) {
    int c = hist[i];
    base[i] = c ? atomicAdd(&bucket_cursor[i], c) : 0;
    hist[i] = 0;  // reuse as running rank
  }
  __syncthreads();
  for (long long e = beg + threadIdx.x; e < end; e += BLK) {
    int s = edges[e];
    int d = edges[E + e];
    int b = d >> 8;
    int r = atomicAdd(&hist[b], 1);
    tmp_out[base[b] + r] = (s << 8) | (d & 255);  // s < 2^18 -> packed < 2^26
  }
}

__global__ __launch_bounds__(BLK)
void k_bfinal(const int* __restrict__ tmp_in, const int* __restrict__ bucket_start, int n,
              int* __restrict__ row_start, int* __restrict__ counts,
              float* __restrict__ dinv, int* __restrict__ col) {
  __shared__ int cnt[256];
  __shared__ int scan[256];
  __shared__ int cur[256];
  const int b = blockIdx.x, t = threadIdx.x;
  const int seg0 = bucket_start[b], seg1 = bucket_start[b + 1];
  cnt[t] = 0;
  __syncthreads();
  for (int i = seg0 + t; i < seg1; i += BLK) atomicAdd(&cnt[tmp_in[i] & 255], 1);
  __syncthreads();
  int v0 = cnt[t];
  scan[t] = v0;
  __syncthreads();
  for (int off = 1; off < 256; off <<= 1) {
    int x = (t >= off) ? scan[t - off] : 0;
    __syncthreads();
    scan[t] += x;
    __syncthreads();
  }
  int loff = scan[t] - v0;  // exclusive local offset
  int v = b * 256 + t;
  if (v < n) {
    row_start[v] = seg0 + loff;
    counts[v] = v0;
    dinv[v] = rsqrtf((float)v0 + 1.0f);  // +1 self-loop
  }
  cur[t] = loff;
  __syncthreads();
  for (int i = seg0 + t; i < seg1; i += BLK) {
    int p = tmp_in[i];
    int r = atomicAdd(&cur[p & 255], 1);
    col[seg0 + r] = p >> 8;
  }
}

// ================= layer-1 GEMM, register-blocked + pipelined staging, bf16 out =================

#define XSTR 260

__global__ __launch_bounds__(BLK)
void k_gemm1(const float* __restrict__ in, const float* __restrict__ W,
             const float* __restrict__ dinv, unsigned* __restrict__ hs1, int n) {
  __shared__ float Xt[33 * XSTR];
  __shared__ float Wl[33 * 64];
  const int t = threadIdx.x;
  const int v0 = blockIdx.x * 256;
  const int tx = t & 7;
  const int ty = t >> 3;

  float xf[33];
  float wf[9];

  float acc[8][8];
#pragma unroll
  for (int i = 0; i < 8; ++i)
#pragma unroll
    for (int j = 0; j < 8; ++j) acc[i][j] = 0.f;

#pragma unroll
  for (int i = 0; i < 33; ++i) {
    int e = t + i * 256;
    int row = e / 33, c = e - row * 33;
    int v = v0 + row;
    xf[i] = (v < n) ? in[(size_t)v * 165 + c] : 0.f;
  }
#pragma unroll
  for (int i = 0; i < 9; ++i) {
    int e = t + i * 256;
    wf[i] = (e < 2112) ? W[e] : 0.f;
  }

  for (int kc = 0; kc < 165; kc += 33) {
    __syncthreads();
#pragma unroll
    for (int i = 0; i < 33; ++i) {
      int e = t + i * 256;
      int row = e / 33, c = e - row * 33;
      Xt[c * XSTR + row] = xf[i];
    }
#pragma unroll
    for (int i = 0; i < 9; ++i) {
      int e = t + i * 256;
      if (e < 2112) Wl[e] = wf[i];
    }
    __syncthreads();

    if (kc + 33 < 165) {
      int kn = kc + 33;
#pragma unroll
      for (int i = 0; i < 33; ++i) {
        int e = t + i * 256;
        int row = e / 33, c = e - row * 33;
        int v = v0 + row;
        xf[i] = (v < n) ? in[(size_t)v * 165 + kn + c] : 0.f;
      }
#pragma unroll
      for (int i = 0; i < 9; ++i) {
        int e = t + i * 256;
        wf[i] = (e < 2112) ? W[kn * 64 + e] : 0.f;
      }
    }

    for (int k = 0; k < 33; ++k) {
      const float4 xa = *(const float4*)&Xt[k * XSTR + ty * 8];
      const float4 xb = *(const float4*)&Xt[k * XSTR + ty * 8 + 4];
      const float4 wa = *(const float4*)&Wl[k * 64 + tx * 8];
      const float4 wb = *(const float4*)&Wl[k * 64 + tx * 8 + 4];
      const float xm[8] = {xa.x, xa.y, xa.z, xa.w, xb.x, xb.y, xb.z, xb.w};
      const float wc[8] = {wa.x, wa.y, wa.z, wa.w, wb.x, wb.y, wb.z, wb.w};
#pragma unroll
      for (int mi = 0; mi < 8; ++mi)
#pragma unroll
        for (int ci = 0; ci < 8; ++ci)
          acc[mi][ci] = fmaf(xm[mi], wc[ci], acc[mi][ci]);
    }
  }

#pragma unroll
  for (int mi = 0; mi < 8; ++mi) {
    int v = v0 + ty * 8 + mi;
    if (v < n) {
      float dv = dinv[v];
      uint4 r;
      r.x = pack2(acc[mi][0] * dv, acc[mi][1] * dv);
      r.y = pack2(acc[mi][2] * dv, acc[mi][3] * dv);
      r.z = pack2(acc[mi][4] * dv, acc[mi][5] * dv);
      r.w = pack2(acc[mi][6] * dv, acc[mi][7] * dv);
      ((uint4*)(hs1 + (size_t)v * 32))[tx] = r;
    }
  }
}

// ================= fused gather(64,bf16) + bias/ReLU + GEMM 64->16 =================
// wave per node; lane = (sub=lane>>5, u=lane&31); each lane covers channels (2u,2u+1).
// After gather + xor(32) reduce, all lanes hold agg pair -> relu -> in-wave shuffle GEMM.

__global__ __launch_bounds__(BLK)
void k_gather64g2(const unsigned* __restrict__ hs1, const int* __restrict__ row_start,
                  const int* __restrict__ counts, const int* __restrict__ col,
                  const float* __restrict__ dinv, const float* __restrict__ b1,
                  const float* __restrict__ W2, unsigned* __restrict__ hs2, int n) {
  __shared__ float W2l[64 * 16];
  for (int i = threadIdx.x; i < 64 * 16; i += BLK) W2l[i] = W2[i];
  __syncthreads();

  int wave = threadIdx.x >> 6, lane = threadIdx.x & 63;
  int v = blockIdx.x * 4 + wave;
  if (v >= n) return;
  int sub = lane >> 5, u = lane & 31;
  int beg = row_start[v], cnt = counts[v];

  float a0, a1;
  if (sub == 0) {
    unsigned p = hs1[(size_t)v * 32 + u];  // self-loop
    a0 = bf_lo(p); a1 = bf_hi(p);
  } else {
    a0 = 0.f; a1 = 0.f;
  }

  int e = sub;
  for (; e + 6 < cnt; e += 8) {
    int s0 = col[beg + e];
    int s1 = col[beg + e + 2];
    int s2 = col[beg + e + 4];
    int s3 = col[beg + e + 6];
    unsigned p0 = hs1[(size_t)s0 * 32 + u];
    unsigned p1 = hs1[(size_t)s1 * 32 + u];
    unsigned p2 = hs1[(size_t)s2 * 32 + u];
    unsigned p3 = hs1[(size_t)s3 * 32 + u];
    a0 += (bf_lo(p0) + bf_lo(p1)) + (bf_lo(p2) + bf_lo(p3));
    a1 += (bf_hi(p0) + bf_hi(p1)) + (bf_hi(p2) + bf_hi(p3));
  }
  for (; e < cnt; e += 2) {
    unsigned p = hs1[(size_t)col[beg + e] * 32 + u];
    a0 += bf_lo(p); a1 += bf_hi(p);
  }
  a0 += __shfl_xor(a0, 32);
  a1 += __shfl_xor(a1, 32);

  float dv = dinv[v];
  float2 bb = ((const float2*)b1)[u];
  float r0 = fmaxf(fmaf(a0, dv, bb.x), 0.f);  // relu(agg1[2u])
  float r1 = fmaxf(fmaf(a1, dv, bb.y), 0.f);  // relu(agg1[2u+1])

  // in-wave GEMM2: lane = (o=lane&15, q=lane>>4); k = q*16+i
  int o = lane & 15, q = lane >> 4;
  float part = 0.f;
#pragma unroll
  for (int i = 0; i < 16; i += 2) {
    int k = q * 16 + i;
    float e0 = __shfl(r0, k >> 1);        // channel k (even)
    float e1 = __shfl(r1, k >> 1);        // channel k+1 (odd)
    part = fmaf(e0, W2l[k * 16 + o], part);
    part = fmaf(e1, W2l[(k + 1) * 16 + o], part);
  }
  part += __shfl_xor(part, 16);
  part += __shfl_xor(part, 32);
  float h = part * dv;                     // hs2 channel o (lane<16 valid)
  float hnext = __shfl_xor(h, 1);
  if (lane < 16 && (lane & 1) == 0)
    hs2[(size_t)v * 8 + (o >> 1)] = pack2(h, hnext);
}

// ================= fused gather(16,bf16) + bias/ReLU + GEMM 16->2 =================
// wave per node; lane = (j=lane>>3 edge slot, p=lane&7 -> channels 2p,2p+1)

__global__ __launch_bounds__(BLK)
void k_gather16g3(const unsigned* __restrict__ hs2, const int* __restrict__ row_start,
                  const int* __restrict__ counts, const int* __restrict__ col,
                  const float* __restrict__ dinv, const float* __restrict__ b2,
                  const float* __restrict__ W3, float* __restrict__ hs3, int n) {
  int wave = threadIdx.x >> 6, lane = threadIdx.x & 63;
  int v = blockIdx.x * 4 + wave;
  if (v >= n) return;
  int j = lane >> 3, p = lane & 7;
  int beg = row_start[v], cnt = counts[v];

  float a0 = 0.f, a1 = 0.f;
  int e = j;
  for (; e + 8 < cnt; e += 16) {
    unsigned pk0 = hs2[(size_t)col[beg + e] * 8 + p];
    unsigned pk1 = hs2[(size_t)col[beg + e + 8] * 8 + p];
    a0 += bf_lo(pk0) + bf_lo(pk1);
    a1 += bf_hi(pk0) + bf_hi(pk1);
  }
  if (e < cnt) {
    unsigned pk = hs2[(size_t)col[beg + e] * 8 + p];
    a0 += bf_lo(pk); a1 += bf_hi(pk);
  }
  a0 += __shfl_xor(a0, 8);  a1 += __shfl_xor(a1, 8);
  a0 += __shfl_xor(a0, 16); a1 += __shfl_xor(a1, 16);
  a0 += __shfl_xor(a0, 32); a1 += __shfl_xor(a1, 32);

  unsigned ps = hs2[(size_t)v * 8 + p];  // self-loop
  a0 += bf_lo(ps); a1 += bf_hi(ps);

  float dv = dinv[v];
  float2 bb = ((const float2*)b2)[p];
  float r0 = fmaxf(fmaf(a0, dv, bb.x), 0.f);
  float r1 = fmaxf(fmaf(a1, dv, bb.y), 0.f);

  // GEMM3: out[o] = sum_k relu(agg2[k]) * W3[k][o]; channel 2i->r0@lane i, 2i+1->r1@lane i
  int o = lane & 1;
  float part = 0.f;
#pragma unroll
  for (int i = 0; i < 8; ++i) {
    float e0 = __shfl(r0, i);
    float e1 = __shfl(r1, i);
    part = fmaf(e0, W3[(2 * i) * 2 + o], part);
    part = fmaf(e1, W3[(2 * i + 1) * 2 + o], part);
  }
  if (lane < 2) hs3[(size_t)v * 2 + o] = part * dv;
}

// ================= final gather(2,fp32) + bias + log-softmax =================

__global__ void k_gather2_lsm(const float* __restrict__ hs3, const int* __restrict__ row_start,
                              const int* __restrict__ counts, const int* __restrict__ col,
                              const float* __restrict__ dinv, const float* __restrict__ b,
                              float* __restrict__ out, int n) {
  int v = blockIdx.x * blockDim.x + threadIdx.x;
  if (v >= n) return;
  const float2* hs2v = (const float2*)hs3;
  int beg = row_start[v], cnt = counts[v];
  float2 self = hs2v[v];
  float a0 = self.x, a1 = self.y;
  for (int e = 0; e < cnt; ++e) {
    float2 m = hs2v[col[beg + e]];
    a0 += m.x;
    a1 += m.y;
  }
  float dv = dinv[v];
  a0 = fmaf(a0, dv, b[0]);
  a1 = fmaf(a1, dv, b[1]);
  float m = fmaxf(a0, a1);
  float l = m + logf(expf(a0 - m) + expf(a1 - m));
  out[2 * v] = a0 - l;
  out[2 * v + 1] = a1 - l;
}

// ================= launch =================

extern "C" void kernel_launch(void* const* d_in, const int* in_sizes, int n_in,
                              void* d_out, int out_size, void* d_ws, size_t ws_size,
                              hipStream_t stream) {
  const float* x = (const float*)d_in[0];
  const int* edges = (const int*)d_in[1];   // int32
  const float* W1 = (const float*)d_in[2];
  const float* b1 = (const float*)d_in[3];
  const float* W2 = (const float*)d_in[4];
  const float* b2 = (const float*)d_in[5];
  const float* W3 = (const float*)d_in[6];
  const float* b3 = (const float*)d_in[7];
  float* out = (float*)d_out;

  const int N = in_sizes[0] / 165;
  const long long E = in_sizes[1] / 2;
  const int nbuk = (N + 255) >> 8;          // 782

  // workspace layout (16B-aligned chunks)
  char* w = (char*)d_ws;
  int* counts        = (int*)w;  w += (size_t)N * 4;
  int* row_start     = (int*)w;  w += (size_t)N * 4;
  float* dinv        = (float*)w; w += (size_t)N * 4;
  int* bucket_counts = (int*)w;  w += (NBUK_MAX + 4) * 4;
  int* bucket_start  = (int*)w;  w += (NBUK_MAX + 4) * 4;
  int* bucket_cursor = (int*)w;  w += (NBUK_MAX + 4) * 4;
  int* col           = (int*)w;  w += (size_t)E * 4;
  unsigned* hs1      = (unsigned*)w; w += (size_t)N * 32 * 4;   // bf16x2, 128B/row
  unsigned* hs2      = (unsigned*)w; w += (size_t)N * 8 * 4;    // bf16x2, 32B/row
  float* hs3         = (float*)w;                                // fp32, 8B/row
  int* tmp = (int*)hs1;  // aliases hs1: consumed by k_bfinal before k_gemm1 writes

  const int gN = (N + BLK - 1) / BLK;
  const int gW = (N + 3) / 4;
  const int NB_PART = 256;
  const long long chunk = (E + NB_PART - 1) / NB_PART;

  // ---- CSR build (binning) + dinv ----
  k_zero<<<(nbuk + BLK - 1) / BLK, BLK, 0, stream>>>(bucket_counts, nbuk);
  k_bcount<<<NB_PART, BLK, 0, stream>>>(edges, E, chunk, nbuk, bucket_counts);
  k_bscan<<<1, 1024, 0, stream>>>(bucket_counts, nbuk, bucket_start, bucket_cursor);
  k_bscatter<<<NB_PART, BLK, 0, stream>>>(edges, E, chunk, nbuk, bucket_cursor, tmp);
  k_bfinal<<<nbuk, BLK, 0, stream>>>(tmp, bucket_start, N, row_start, counts, dinv, col);

  // ---- layer 1: 165 -> 64 (bf16 out) ----
  k_gemm1<<<gN, BLK, 0, stream>>>(x, W1, dinv, hs1, N);

  // ---- layer 1 aggregate + layer 2 transform (fused) ----
  k_gather64g2<<<gW, BLK, 0, stream>>>(hs1, row_start, counts, col, dinv, b1, W2, hs2, N);

  // ---- layer 2 aggregate + layer 3 transform (fused) ----
  k_gather16g3<<<gW, BLK, 0, stream>>>(hs2, row_start, counts, col, dinv, b2, W3, hs3, N);

  // ---- layer 3 aggregate + bias + log-softmax ----
  k_gather2_lsm<<<gN, BLK, 0, stream>>>(hs3, row_start, counts, col, dinv, b3, out, N);
}